// Round 12
// baseline (630.939 us; speedup 1.0000x reference)
//
#include <hip/hip_runtime.h>
#include <hip/hip_bf16.h>
#include <math.h>

#define N_LIGC 1024
#define NTOT 9216
#define KNN 48
#define HID 256
#define DEPTHC 5
#define ETOT (N_LIGC*KNN)
#define KBINS 4096

typedef unsigned short u16;
typedef __attribute__((ext_vector_type(8))) short bf16x8;
typedef __attribute__((ext_vector_type(4))) float f32x4;

__device__ __forceinline__ float freq_f(int i){
  double p = (double)(1 << (2*i));
  return (float)((2.0*3.14159265358979323846)*p/15.0);
}
__device__ __forceinline__ float silu_f(float v){
  return v*__builtin_amdgcn_rcpf(1.0f+__expf(-v));
}
__device__ __forceinline__ float sigm_f(float v){
  return __builtin_amdgcn_rcpf(1.0f+__expf(-v));
}
__device__ __forceinline__ u16 f2b(float f){
  unsigned int u = __float_as_uint(f);
  return (u16)((u + 0x7fffu + ((u>>16)&1u)) >> 16);
}
__device__ __forceinline__ float b2f(u16 u){
  union { unsigned int i; float f; } c; c.i = ((unsigned int)u)<<16; return c.f;
}
__device__ __forceinline__ u16 f2b_p(float f){
  union { __hip_bfloat16 h; u16 u; } c; c.h = __float2bfloat16(f); return c.u;
}

// ---- pack fp32 [L][srcK][N] rows [kOff,kOff+Keff) -> bf16 B-frag layout
__device__ __forceinline__ void pack_one(const float* __restrict__ src,
    u16* __restrict__ dst, int srcK, int kOff, int Keff, int Kp, int N, int idx)
{
  int lane = idx & 63;
  int rest = idx >> 6;
  int Nt = N >> 4;
  int n0 = rest % Nt;
  int rest2 = rest / Nt;
  int Kt = Kp >> 5;
  int k0 = rest2 % Kt;
  int layer = rest2 / Kt;
  int kq = lane >> 4, nl = lane & 15;
  int kb = k0*32 + kq*8, n = n0*16 + nl;
  u16 o[8];
  #pragma unroll
  for (int j=0;j<8;j++){
    int k = kb + j;
    float v = (k < Keff) ? src[((size_t)layer*srcK + kOff + k)*N + n] : 0.f;
    o[j] = f2b_p(v);
  }
  *(uint4*)(dst + (size_t)idx*8) = *(uint4*)o;
}

__global__ __launch_bounds__(256) void k_packall(
    const float* eW1, const float* eW2, const float* nW1, const float* nW2,
    const float* cW1, const float* cW2, const float* Wout,
    u16* eW1abP, u16* eW1cP, u16* eW2p, u16* nW1p, u16* nW2p,
    u16* cW1abP, u16* cW1cP, u16* cW2p, u16* WoutP)
{
  int idx = blockIdx.x*256 + threadIdx.x;
  if (idx < 81920){ pack_one(eW1, eW1abP, 536, 0,   512, 512, 256, idx); return; } idx -= 81920;
  if (idx < 5120 ){ pack_one(eW1, eW1cP,  536, 512, 24,  32,  256, idx); return; } idx -= 5120;
  if (idx < 40960){ pack_one(eW2, eW2p,   256, 0,   256, 256, 256, idx); return; } idx -= 40960;
  if (idx < 81920){ pack_one(nW1, nW1p,   512, 0,   512, 512, 256, idx); return; } idx -= 81920;
  if (idx < 40960){ pack_one(nW2, nW2p,   256, 0,   256, 256, 256, idx); return; } idx -= 40960;
  if (idx < 81920){ pack_one(cW1, cW1abP, 536, 0,   512, 512, 256, idx); return; } idx -= 81920;
  if (idx < 5120 ){ pack_one(cW1, cW1cP,  536, 512, 24,  32,  256, idx); return; } idx -= 5120;
  if (idx < 40960){ pack_one(cW2, cW2p,   256, 0,   256, 256, 256, idx); return; } idx -= 40960;
  if (idx < 1024 ){ pack_one(Wout, WoutP, 256, 0,   256, 256, 32,  idx); return; }
}

// ---- fused embed + h-init ----
__global__ __launch_bounds__(256) void k_embed_hinit(
    const float* __restrict__ protPos, const int* __restrict__ protEle,
    const int* __restrict__ protAA, const int* __restrict__ protBB,
    const float* __restrict__ XtPos, const float* __restrict__ XtFeat,
    const int* __restrict__ tArr, const float* __restrict__ WtTime,
    const float* __restrict__ Wele, const float* __restrict__ Waa,
    const float* __restrict__ Wbb,
    const float* __restrict__ Win, const float* __restrict__ bin,
    float* __restrict__ X0, float* __restrict__ X1,
    float* __restrict__ h, u16* __restrict__ h_bf)
{
  __shared__ float sF[8*40];
  int blk=blockIdx.x, tid=threadIdx.x;
  int n0=blk*8;
  for (int x=tid; x<344; x+=256){
    if (x < 320){
      int n = x/40, k = x%40;
      int node = n0+n;
      float v;
      if (node < N_LIGC){
        if (k < 32) v = XtFeat[node*32+k];
        else        v = WtTime[tArr[node]*8 + (k-32)];
      } else {
        int p = node - N_LIGC;
        if (k < 16)      v = Wele[protEle[p]*16 + k];
        else if (k < 32) v = Waa[protAA[p]*16 + (k-16)];
        else             v = Wbb[protBB[p]*8 + (k-32)];
      }
      sF[n*40+k] = v;
    } else {
      int r = x-320; int n = r/3, c = r%3;
      int node = n0+n;
      float v = (node < N_LIGC) ? XtPos[node*3+c] : protPos[(node-N_LIGC)*3+c];
      X0[node*3+c] = v; X1[node*3+c] = v;
    }
  }
  __syncthreads();
  float acc[8];
  float b=bin[tid];
  #pragma unroll
  for (int n=0;n<8;n++) acc[n]=b;
  for (int k=0;k<40;k++){
    float w=Win[k*HID+tid];
    #pragma unroll
    for (int n=0;n<8;n++) acc[n]+=sF[n*40+k]*w;
  }
  #pragma unroll
  for (int n=0;n<8;n++){
    h[(size_t)(n0+n)*HID+tid]=acc[n];
    h_bf[(size_t)(n0+n)*HID+tid]=f2b_p(acc[n]);
  }
}

// ---- KNN: radix-histogram top-K ----
__global__ __launch_bounds__(256) void k_knn(const float* __restrict__ X,
    int* __restrict__ col, float* __restrict__ emb0)
{
  __shared__ unsigned int hist[KBINS];
  __shared__ unsigned int part[256];
  __shared__ float selD[KNN];
  __shared__ int   candI[512];
  __shared__ float candV[512];
  __shared__ int sB, sCless, sNeed, sNsel, sNcand;
  int b = blockIdx.x, tid = threadIdx.x;
  for (int i=tid;i<KBINS;i+=256) hist[i]=0u;
  if (tid==0){ sNsel=0; sNcand=0; }
  float px = X[b*3+0], py = X[b*3+1], pz = X[b*3+2];
  __syncthreads();
  #pragma unroll 4
  for (int j=0;j<36;j++){
    int i = tid + 256*j;
    float dx = __fsub_rn(px, X[i*3+0]);
    float dy = __fsub_rn(py, X[i*3+1]);
    float dz = __fsub_rn(pz, X[i*3+2]);
    float d2 = __fadd_rn(__fadd_rn(__fmul_rn(dx,dx),__fmul_rn(dy,dy)),__fmul_rn(dz,dz));
    if (i==b) d2 = INFINITY;
    unsigned key = __float_as_uint(d2) >> 19;
    atomicAdd(&hist[key], 1u);
  }
  __syncthreads();
  {
    unsigned s=0;
    #pragma unroll 4
    for (int k=0;k<16;k++) s += hist[tid*16+k];
    part[tid]=s;
  }
  __syncthreads();
  if (tid==0){
    unsigned c=0; int chunk=0;
    for (int t=0;t<256;t++){
      if (c + part[t] >= (unsigned)KNN){ chunk=t; break; }
      c += part[t];
    }
    int bin = chunk*16;
    for (;;bin++){
      unsigned hh = hist[bin];
      if (c + hh >= (unsigned)KNN) break;
      c += hh;
    }
    sB = bin; sCless = (int)c; sNeed = KNN - (int)c;
  }
  __syncthreads();
  int B = sB;
  #pragma unroll 4
  for (int j=0;j<36;j++){
    int i = tid + 256*j;
    float dx = __fsub_rn(px, X[i*3+0]);
    float dy = __fsub_rn(py, X[i*3+1]);
    float dz = __fsub_rn(pz, X[i*3+2]);
    float d2 = __fadd_rn(__fadd_rn(__fmul_rn(dx,dx),__fmul_rn(dy,dy)),__fmul_rn(dz,dz));
    if (i==b) d2 = INFINITY;
    int key = (int)(__float_as_uint(d2) >> 19);
    if (key < B){
      int p = atomicAdd(&sNsel, 1);
      col[b*KNN+p] = i; selD[p] = d2;
    } else if (key == B){
      int c = atomicAdd(&sNcand, 1);
      if (c < 512){ candI[c] = i; candV[c] = d2; }
    }
  }
  __syncthreads();
  if (tid < 64){
    int m = sNcand; if (m > 512) m = 512;
    int need = sNeed, base = sCless;
    float cv[8]; int ci[8];
    #pragma unroll
    for (int k=0;k<8;k++){
      int c = tid + 64*k;
      if (c < m){ ci[k]=candI[c]; cv[k]=candV[c]; }
      else      { ci[k]=0x7fffffff; cv[k]=INFINITY; }
    }
    for (int it=0; it<need; it++){
      float bv=INFINITY; int bi=0x7fffffff; int bk=0;
      #pragma unroll
      for (int k=0;k<8;k++){
        if (cv[k]<bv || (cv[k]==bv && ci[k]<bi)){ bv=cv[k]; bi=ci[k]; bk=k; }
      }
      int bslot = tid + 64*bk;
      #pragma unroll
      for (int off=32; off>=1; off>>=1){
        float ov = __shfl_down(bv, off);
        int   oi = __shfl_down(bi, off);
        int   os = __shfl_down(bslot, off);
        if (ov < bv || (ov==bv && oi<bi)){ bv=ov; bi=oi; bslot=os; }
      }
      int wslot = __shfl(bslot, 0);
      if (tid==0){ col[b*KNN+base+it]=bi; selD[base+it]=bv; }
      if ((wslot & 63) == tid) cv[wslot >> 6] = INFINITY;
    }
  }
  __syncthreads();
  if (tid < KNN){
    float d = sqrtf(selD[tid] + 1e-8f);
    int base = (b*KNN+tid)*12;
    #pragma unroll
    for (int i=0;i<6;i++){
      float fr = freq_f(i);
      emb0[base+i]   = sinf(d*fr);
      emb0[base+6+i] = cosf(d*fr);
    }
  }
}

// ---- k_pq: initial Q/R for layer 0 edge stage ----
__global__ __launch_bounds__(256) void k_pq(const u16* __restrict__ h_bf,
    const u16* __restrict__ Wab, float* __restrict__ R, u16* __restrict__ Qb, int l)
{
  __shared__ __align__(16) u16 sA[32*264];
  int blk=blockIdx.x, tid=threadIdx.x;
  int lane=tid&63, ng=tid>>6, quad=lane>>4, nl=lane&15;
  for (int t=tid; t<32*32; t+=256){
    int i=t>>5, q=t&31;
    uint4 v = ((const uint4*)(h_bf + (size_t)(blk*32+i)*HID))[q];
    *(uint4*)(sA + i*264 + q*8) = v;
  }
  __syncthreads();
  const u16* Wl = Wab + (size_t)l*512*HID;
  f32x4 zero4 = {0.f,0.f,0.f,0.f};
  f32x4 aQ[2][4];
  #pragma unroll
  for (int i=0;i<2;i++){ aQ[i][0]=zero4; aQ[i][1]=zero4; aQ[i][2]=zero4; aQ[i][3]=zero4; }
  #pragma unroll 2
  for (int k0=0;k0<8;k0++){
    bf16x8 a0 = *(const bf16x8*)(sA + (0*16+nl)*264 + k0*32 + quad*8);
    bf16x8 a1 = *(const bf16x8*)(sA + (1*16+nl)*264 + k0*32 + quad*8);
    const u16* wb = Wl + ((size_t)((k0+8)*16 + ng*4)*64 + lane)*8;
    bf16x8 b0 = *(const bf16x8*)(wb);
    bf16x8 b1 = *(const bf16x8*)(wb + 512);
    bf16x8 b2 = *(const bf16x8*)(wb + 1024);
    bf16x8 b3 = *(const bf16x8*)(wb + 1536);
    aQ[0][0]=__builtin_amdgcn_mfma_f32_16x16x32_bf16(a0,b0,aQ[0][0],0,0,0);
    aQ[0][1]=__builtin_amdgcn_mfma_f32_16x16x32_bf16(a0,b1,aQ[0][1],0,0,0);
    aQ[0][2]=__builtin_amdgcn_mfma_f32_16x16x32_bf16(a0,b2,aQ[0][2],0,0,0);
    aQ[0][3]=__builtin_amdgcn_mfma_f32_16x16x32_bf16(a0,b3,aQ[0][3],0,0,0);
    aQ[1][0]=__builtin_amdgcn_mfma_f32_16x16x32_bf16(a1,b0,aQ[1][0],0,0,0);
    aQ[1][1]=__builtin_amdgcn_mfma_f32_16x16x32_bf16(a1,b1,aQ[1][1],0,0,0);
    aQ[1][2]=__builtin_amdgcn_mfma_f32_16x16x32_bf16(a1,b2,aQ[1][2],0,0,0);
    aQ[1][3]=__builtin_amdgcn_mfma_f32_16x16x32_bf16(a1,b3,aQ[1][3],0,0,0);
  }
  #pragma unroll
  for (int mt=0;mt<2;mt++)
  #pragma unroll
  for (int nt=0;nt<4;nt++){
    int n = ng*64 + nt*16 + nl;
    #pragma unroll
    for (int r=0;r<4;r++){
      int node = blk*32 + mt*16 + quad*4 + r;
      Qb[(size_t)node*HID + n] = f2b(aQ[mt][nt][r]);
    }
  }
  if (blk < 32){
    f32x4 aR[2][4];
    #pragma unroll
    for (int i=0;i<2;i++){ aR[i][0]=zero4; aR[i][1]=zero4; aR[i][2]=zero4; aR[i][3]=zero4; }
    #pragma unroll 2
    for (int k0=0;k0<8;k0++){
      bf16x8 a0 = *(const bf16x8*)(sA + (0*16+nl)*264 + k0*32 + quad*8);
      bf16x8 a1 = *(const bf16x8*)(sA + (1*16+nl)*264 + k0*32 + quad*8);
      const u16* wb = Wl + ((size_t)(k0*16 + ng*4)*64 + lane)*8;
      bf16x8 b0 = *(const bf16x8*)(wb);
      bf16x8 b1 = *(const bf16x8*)(wb + 512);
      bf16x8 b2 = *(const bf16x8*)(wb + 1024);
      bf16x8 b3 = *(const bf16x8*)(wb + 1536);
      aR[0][0]=__builtin_amdgcn_mfma_f32_16x16x32_bf16(a0,b0,aR[0][0],0,0,0);
      aR[0][1]=__builtin_amdgcn_mfma_f32_16x16x32_bf16(a0,b1,aR[0][1],0,0,0);
      aR[0][2]=__builtin_amdgcn_mfma_f32_16x16x32_bf16(a0,b2,aR[0][2],0,0,0);
      aR[0][3]=__builtin_amdgcn_mfma_f32_16x16x32_bf16(a0,b3,aR[0][3],0,0,0);
      aR[1][0]=__builtin_amdgcn_mfma_f32_16x16x32_bf16(a1,b0,aR[1][0],0,0,0);
      aR[1][1]=__builtin_amdgcn_mfma_f32_16x16x32_bf16(a1,b1,aR[1][1],0,0,0);
      aR[1][2]=__builtin_amdgcn_mfma_f32_16x16x32_bf16(a1,b2,aR[1][2],0,0,0);
      aR[1][3]=__builtin_amdgcn_mfma_f32_16x16x32_bf16(a1,b3,aR[1][3],0,0,0);
    }
    #pragma unroll
    for (int mt=0;mt<2;mt++)
    #pragma unroll
    for (int nt=0;nt<4;nt++){
      int n = ng*64 + nt*16 + nl;
      #pragma unroll
      for (int r=0;r<4;r++){
        int node = blk*32 + mt*16 + quad*4 + r;
        R[(size_t)node*HID + n] = aR[mt][nt][r];
      }
    }
  }
}

// ---- edge combine (48 edges/block, grid 1024, single in-place LDS buffer) ----
__global__ __launch_bounds__(256) void k_comb_edge(
    const u16* __restrict__ Qb, const float* __restrict__ R,
    const float* __restrict__ xc,
    const int* __restrict__ colIdx, const float* __restrict__ emb0,
    const u16* __restrict__ W1cP, const float* __restrict__ B1,
    const u16* __restrict__ W2p, const float* __restrict__ B2,
    const float* __restrict__ attW, const float* __restrict__ attB,
    u16* __restrict__ agg_bf, int l)
{
  __shared__ __align__(16) u16 sBuf[48*264];   // Q -> m1 -> m2 in place
  __shared__ __align__(16) u16 sEA[48*40];
  __shared__ float sR[256];
  __shared__ int sCol[48];
  __shared__ float sD[48];
  __shared__ float sSig[48];
  __shared__ float sDot[48][4];

  int row = blockIdx.x, tid = threadIdx.x;
  int lane = tid & 63, ng = tid >> 6;
  int quad = lane >> 4, nl = lane & 15;

  if (tid < 48) sCol[tid] = colIdx[(size_t)row*KNN + tid];
  sR[tid] = R[(size_t)row*HID + tid];
  __syncthreads();
  for (int t = tid; t < 48*32; t += 256){
    int e = t >> 5, q = t & 31;
    uint4 v = ((const uint4*)(Qb + (size_t)sCol[e]*HID))[q];
    *(uint4*)(sBuf + e*264 + q*8) = v;
  }
  if (tid < 48){
    int cg = sCol[tid];
    float dx = xc[row*3+0]-xc[cg*3+0];
    float dy = xc[row*3+1]-xc[cg*3+1];
    float dz = xc[row*3+2]-xc[cg*3+2];
    float d = sqrtf(dx*dx+dy*dy+dz*dz + 1e-8f);
    sD[tid] = d;
    u16* ea = sEA + tid*40;
    #pragma unroll
    for (int i=0;i<12;i++) ea[12+i] = f2b_p(emb0[((size_t)row*KNN + tid)*12 + i]);
    #pragma unroll
    for (int i=24;i<32;i++) ea[i] = 0;
  }
  __syncthreads();
  for (int t=tid; t<288; t+=256){
    int e = t/6, i = t - 6*e;
    float fr = 0.41887903f * (float)(1 << (2*i));
    float x = sD[e]*fr;
    u16* ea = sEA + e*40;
    ea[i]   = f2b(__sinf(x));
    ea[6+i] = f2b(__cosf(x));
  }
  __syncthreads();

  f32x4 zero4 = {0.f,0.f,0.f,0.f};
  f32x4 acc[3][4];
  #pragma unroll
  for (int i=0;i<3;i++){ acc[i][0]=zero4; acc[i][1]=zero4; acc[i][2]=zero4; acc[i][3]=zero4; }
  {
    const u16* Wc = W1cP + (size_t)l*32*HID;
    const u16* wb = Wc + ((size_t)(ng*4)*64 + lane)*8;
    bf16x8 b0 = *(const bf16x8*)(wb);
    bf16x8 b1 = *(const bf16x8*)(wb + 512);
    bf16x8 b2 = *(const bf16x8*)(wb + 1024);
    bf16x8 b3 = *(const bf16x8*)(wb + 1536);
    bf16x8 a0 = *(const bf16x8*)(sEA + (0*16+nl)*40 + quad*8);
    bf16x8 a1 = *(const bf16x8*)(sEA + (1*16+nl)*40 + quad*8);
    bf16x8 a2 = *(const bf16x8*)(sEA + (2*16+nl)*40 + quad*8);
    acc[0][0]=__builtin_amdgcn_mfma_f32_16x16x32_bf16(a0,b0,acc[0][0],0,0,0);
    acc[0][1]=__builtin_amdgcn_mfma_f32_16x16x32_bf16(a0,b1,acc[0][1],0,0,0);
    acc[0][2]=__builtin_amdgcn_mfma_f32_16x16x32_bf16(a0,b2,acc[0][2],0,0,0);
    acc[0][3]=__builtin_amdgcn_mfma_f32_16x16x32_bf16(a0,b3,acc[0][3],0,0,0);
    acc[1][0]=__builtin_amdgcn_mfma_f32_16x16x32_bf16(a1,b0,acc[1][0],0,0,0);
    acc[1][1]=__builtin_amdgcn_mfma_f32_16x16x32_bf16(a1,b1,acc[1][1],0,0,0);
    acc[1][2]=__builtin_amdgcn_mfma_f32_16x16x32_bf16(a1,b2,acc[1][2],0,0,0);
    acc[1][3]=__builtin_amdgcn_mfma_f32_16x16x32_bf16(a1,b3,acc[1][3],0,0,0);
    acc[2][0]=__builtin_amdgcn_mfma_f32_16x16x32_bf16(a2,b0,acc[2][0],0,0,0);
    acc[2][1]=__builtin_amdgcn_mfma_f32_16x16x32_bf16(a2,b1,acc[2][1],0,0,0);
    acc[2][2]=__builtin_amdgcn_mfma_f32_16x16x32_bf16(a2,b2,acc[2][2],0,0,0);
    acc[2][3]=__builtin_amdgcn_mfma_f32_16x16x32_bf16(a2,b3,acc[2][3],0,0,0);
  }
  // stage-1 epilogue in place (each (m,n) owned by exactly one thread)
  #pragma unroll
  for (int mt=0;mt<3;mt++)
  #pragma unroll
  for (int nt=0;nt<4;nt++){
    int n = ng*64 + nt*16 + nl;
    float bb = B1[l*HID + n] + sR[n];
    #pragma unroll
    for (int r=0;r<4;r++){
      int m = mt*16 + quad*4 + r;
      float v = acc[mt][nt][r] + bb + b2f(sBuf[m*264 + n]);
      sBuf[m*264 + n] = f2b(silu_f(v));
    }
  }
  __syncthreads();

  f32x4 acc2[3][4];
  #pragma unroll
  for (int i=0;i<3;i++){ acc2[i][0]=zero4; acc2[i][1]=zero4; acc2[i][2]=zero4; acc2[i][3]=zero4; }
  const u16* W2 = W2p + (size_t)l*HID*HID;
  #pragma unroll 2
  for (int k0=0;k0<8;k0++){
    bf16x8 a0 = *(const bf16x8*)(sBuf + (0*16+nl)*264 + k0*32 + quad*8);
    bf16x8 a1 = *(const bf16x8*)(sBuf + (1*16+nl)*264 + k0*32 + quad*8);
    bf16x8 a2 = *(const bf16x8*)(sBuf + (2*16+nl)*264 + k0*32 + quad*8);
    const u16* wb = W2 + ((size_t)(k0*16 + ng*4)*64 + lane)*8;
    bf16x8 b0 = *(const bf16x8*)(wb);
    bf16x8 b1 = *(const bf16x8*)(wb + 512);
    bf16x8 b2 = *(const bf16x8*)(wb + 1024);
    bf16x8 b3 = *(const bf16x8*)(wb + 1536);
    acc2[0][0]=__builtin_amdgcn_mfma_f32_16x16x32_bf16(a0,b0,acc2[0][0],0,0,0);
    acc2[0][1]=__builtin_amdgcn_mfma_f32_16x16x32_bf16(a0,b1,acc2[0][1],0,0,0);
    acc2[0][2]=__builtin_amdgcn_mfma_f32_16x16x32_bf16(a0,b2,acc2[0][2],0,0,0);
    acc2[0][3]=__builtin_amdgcn_mfma_f32_16x16x32_bf16(a0,b3,acc2[0][3],0,0,0);
    acc2[1][0]=__builtin_amdgcn_mfma_f32_16x16x32_bf16(a1,b0,acc2[1][0],0,0,0);
    acc2[1][1]=__builtin_amdgcn_mfma_f32_16x16x32_bf16(a1,b1,acc2[1][1],0,0,0);
    acc2[1][2]=__builtin_amdgcn_mfma_f32_16x16x32_bf16(a1,b2,acc2[1][2],0,0,0);
    acc2[1][3]=__builtin_amdgcn_mfma_f32_16x16x32_bf16(a1,b3,acc2[1][3],0,0,0);
    acc2[2][0]=__builtin_amdgcn_mfma_f32_16x16x32_bf16(a2,b0,acc2[2][0],0,0,0);
    acc2[2][1]=__builtin_amdgcn_mfma_f32_16x16x32_bf16(a2,b1,acc2[2][1],0,0,0);
    acc2[2][2]=__builtin_amdgcn_mfma_f32_16x16x32_bf16(a2,b2,acc2[2][2],0,0,0);
    acc2[2][3]=__builtin_amdgcn_mfma_f32_16x16x32_bf16(a2,b3,acc2[2][3],0,0,0);
  }
  __syncthreads();
  #pragma unroll
  for (int mt=0;mt<3;mt++)
  #pragma unroll
  for (int nt=0;nt<4;nt++){
    int n = ng*64 + nt*16 + nl;
    float bb = B2[l*HID + n];
    #pragma unroll
    for (int r=0;r<4;r++){
      int m = mt*16 + quad*4 + r;
      sBuf[m*264 + n] = f2b(silu_f(acc2[mt][nt][r] + bb));
    }
  }
  __syncthreads();
  if (tid < 192){
    int e = tid >> 2, qq = tid & 3;
    const unsigned int* rowp = (const unsigned int*)(sBuf + e*264 + qq*64);
    const float* wbase = attW + l*HID + qq*64;
    float s = 0.f;
    #pragma unroll 4
    for (int p0=0;p0<32;p0++){
      int p = (p0 + e + 8*qq) & 31;
      unsigned int v = rowp[p];
      s += b2f((u16)(v & 0xffffu))*wbase[2*p] + b2f((u16)(v >> 16))*wbase[2*p+1];
    }
    sDot[e][qq] = s;
  }
  __syncthreads();
  if (tid < 48){
    float s = sDot[tid][0]+sDot[tid][1]+sDot[tid][2]+sDot[tid][3] + attB[l];
    sSig[tid] = sigm_f(s);
  }
  __syncthreads();
  {
    float a = 0.f;
    #pragma unroll 4
    for (int e=0;e<48;e++) a += b2f(sBuf[e*264 + tid])*sSig[e];
    agg_bf[(size_t)row*HID + tid] = f2b(a*0.2f);
  }
}

// ---- node MLP: 16 nodes/block (grid 576), in-place sU, + QC/RC + QE/RE + outh ----
__global__ __launch_bounds__(256) void k_node(
    float* __restrict__ h, u16* __restrict__ h_bf,
    const u16* __restrict__ agg_bf,
    const u16* __restrict__ W1p, const float* __restrict__ B1,
    const u16* __restrict__ W2p, const float* __restrict__ B2,
    const u16* __restrict__ cWab, u16* __restrict__ QbC, float* __restrict__ RC,
    const u16* __restrict__ eWabN, u16* __restrict__ QbE, float* __restrict__ RE, int doE,
    const u16* __restrict__ WoutP, const float* __restrict__ bout,
    float* __restrict__ outH, int doOut, int l)
{
  __shared__ __align__(16) u16 sA[16*520];   // rows: [0..256)=h / later h_new ; [256..512)=agg / later u
  int blk=blockIdx.x, tid=threadIdx.x;
  int lane=tid&63, ng=tid>>6, quad=lane>>4, nl=lane&15;
  int n0 = blk*16;
  for (int t=tid; t<16*64; t+=256){
    int i=t>>6, q=t&63;
    int node = n0+i;
    uint4 v;
    if (q<32) v = ((const uint4*)(h_bf + (size_t)node*HID))[q];
    else if (node < N_LIGC) v = ((const uint4*)(agg_bf + (size_t)node*HID))[q-32];
    else { v.x=0u; v.y=0u; v.z=0u; v.w=0u; }
    *(uint4*)(sA + i*520 + q*8) = v;
  }
  __syncthreads();
  f32x4 zero4 = {0.f,0.f,0.f,0.f};
  f32x4 acc[4];
  acc[0]=zero4; acc[1]=zero4; acc[2]=zero4; acc[3]=zero4;
  const u16* Wp = W1p + (size_t)l*512*HID;
  #pragma unroll 2
  for (int k0=0;k0<16;k0++){
    bf16x8 a0 = *(const bf16x8*)(sA + nl*520 + k0*32 + quad*8);
    const u16* wb = Wp + ((size_t)(k0*16 + ng*4)*64 + lane)*8;
    bf16x8 b0 = *(const bf16x8*)(wb);
    bf16x8 b1 = *(const bf16x8*)(wb + 512);
    bf16x8 b2 = *(const bf16x8*)(wb + 1024);
    bf16x8 b3 = *(const bf16x8*)(wb + 1536);
    acc[0]=__builtin_amdgcn_mfma_f32_16x16x32_bf16(a0,b0,acc[0],0,0,0);
    acc[1]=__builtin_amdgcn_mfma_f32_16x16x32_bf16(a0,b1,acc[1],0,0,0);
    acc[2]=__builtin_amdgcn_mfma_f32_16x16x32_bf16(a0,b2,acc[2],0,0,0);
    acc[3]=__builtin_amdgcn_mfma_f32_16x16x32_bf16(a0,b3,acc[3],0,0,0);
  }
  __syncthreads();   // all GEMM1 reads of agg cols done before u overwrite
  #pragma unroll
  for (int nt=0;nt<4;nt++){
    int n = ng*64 + nt*16 + nl;
    float bb = B1[l*HID + n];
    #pragma unroll
    for (int r=0;r<4;r++){
      int m = quad*4 + r;
      sA[m*520 + 256 + n] = f2b(silu_f(acc[nt][r] + bb));
    }
  }
  __syncthreads();
  f32x4 acc2[4];
  acc2[0]=zero4; acc2[1]=zero4; acc2[2]=zero4; acc2[3]=zero4;
  const u16* W2 = W2p + (size_t)l*HID*HID;
  #pragma unroll 2
  for (int k0=0;k0<8;k0++){
    bf16x8 a0 = *(const bf16x8*)(sA + nl*520 + 256 + k0*32 + quad*8);
    const u16* wb = W2 + ((size_t)(k0*16 + ng*4)*64 + lane)*8;
    bf16x8 b0 = *(const bf16x8*)(wb);
    bf16x8 b1 = *(const bf16x8*)(wb + 512);
    bf16x8 b2 = *(const bf16x8*)(wb + 1024);
    bf16x8 b3 = *(const bf16x8*)(wb + 1536);
    acc2[0]=__builtin_amdgcn_mfma_f32_16x16x32_bf16(a0,b0,acc2[0],0,0,0);
    acc2[1]=__builtin_amdgcn_mfma_f32_16x16x32_bf16(a0,b1,acc2[1],0,0,0);
    acc2[2]=__builtin_amdgcn_mfma_f32_16x16x32_bf16(a0,b2,acc2[2],0,0,0);
    acc2[3]=__builtin_amdgcn_mfma_f32_16x16x32_bf16(a0,b3,acc2[3],0,0,0);
  }
  // h epilogue writes cols 0..255; GEMM2 reads only cols 256..511 -> no barrier needed
  #pragma unroll
  for (int nt=0;nt<4;nt++){
    int n = ng*64 + nt*16 + nl;
    float bb = B2[l*HID + n];
    #pragma unroll
    for (int r=0;r<4;r++){
      int m = quad*4 + r;
      size_t idx = (size_t)(n0+m)*HID + n;
      float v = h[idx] + acc2[nt][r] + bb;
      h[idx] = v;
      u16 bv = f2b(v);
      h_bf[idx] = bv;
      sA[m*520 + n] = bv;
    }
  }
  __syncthreads();

  // QC = h_new @ cW1b
  const u16* Wl = cWab + (size_t)l*512*HID;
  f32x4 q[4];
  q[0]=zero4; q[1]=zero4; q[2]=zero4; q[3]=zero4;
  #pragma unroll 2
  for (int k0=0;k0<8;k0++){
    bf16x8 a0 = *(const bf16x8*)(sA + nl*520 + k0*32 + quad*8);
    const u16* wb = Wl + ((size_t)((k0+8)*16 + ng*4)*64 + lane)*8;
    bf16x8 b0 = *(const bf16x8*)(wb);
    bf16x8 b1 = *(const bf16x8*)(wb + 512);
    bf16x8 b2 = *(const bf16x8*)(wb + 1024);
    bf16x8 b3 = *(const bf16x8*)(wb + 1536);
    q[0]=__builtin_amdgcn_mfma_f32_16x16x32_bf16(a0,b0,q[0],0,0,0);
    q[1]=__builtin_amdgcn_mfma_f32_16x16x32_bf16(a0,b1,q[1],0,0,0);
    q[2]=__builtin_amdgcn_mfma_f32_16x16x32_bf16(a0,b2,q[2],0,0,0);
    q[3]=__builtin_amdgcn_mfma_f32_16x16x32_bf16(a0,b3,q[3],0,0,0);
  }
  #pragma unroll
  for (int nt=0;nt<4;nt++){
    int n = ng*64 + nt*16 + nl;
    #pragma unroll
    for (int r=0;r<4;r++)
      QbC[(size_t)(n0+quad*4+r)*HID + n] = f2b(q[nt][r]);
  }
  if (blk < N_LIGC/16){
    q[0]=zero4; q[1]=zero4; q[2]=zero4; q[3]=zero4;
    #pragma unroll 2
    for (int k0=0;k0<8;k0++){
      bf16x8 a0 = *(const bf16x8*)(sA + nl*520 + k0*32 + quad*8);
      const u16* wb = Wl + ((size_t)(k0*16 + ng*4)*64 + lane)*8;
      bf16x8 b0 = *(const bf16x8*)(wb);
      bf16x8 b1 = *(const bf16x8*)(wb + 512);
      bf16x8 b2 = *(const bf16x8*)(wb + 1024);
      bf16x8 b3 = *(const bf16x8*)(wb + 1536);
      q[0]=__builtin_amdgcn_mfma_f32_16x16x32_bf16(a0,b0,q[0],0,0,0);
      q[1]=__builtin_amdgcn_mfma_f32_16x16x32_bf16(a0,b1,q[1],0,0,0);
      q[2]=__builtin_amdgcn_mfma_f32_16x16x32_bf16(a0,b2,q[2],0,0,0);
      q[3]=__builtin_amdgcn_mfma_f32_16x16x32_bf16(a0,b3,q[3],0,0,0);
    }
    #pragma unroll
    for (int nt=0;nt<4;nt++){
      int n = ng*64 + nt*16 + nl;
      #pragma unroll
      for (int r=0;r<4;r++)
        RC[(size_t)(n0+quad*4+r)*HID + n] = q[nt][r];
    }
  }
  if (doE){
    q[0]=zero4; q[1]=zero4; q[2]=zero4; q[3]=zero4;
    #pragma unroll 2
    for (int k0=0;k0<8;k0++){
      bf16x8 a0 = *(const bf16x8*)(sA + nl*520 + k0*32 + quad*8);
      const u16* wb = eWabN + ((size_t)((k0+8)*16 + ng*4)*64 + lane)*8;
      bf16x8 b0 = *(const bf16x8*)(wb);
      bf16x8 b1 = *(const bf16x8*)(wb + 512);
      bf16x8 b2 = *(const bf16x8*)(wb + 1024);
      bf16x8 b3 = *(const bf16x8*)(wb + 1536);
      q[0]=__builtin_amdgcn_mfma_f32_16x16x32_bf16(a0,b0,q[0],0,0,0);
      q[1]=__builtin_amdgcn_mfma_f32_16x16x32_bf16(a0,b1,q[1],0,0,0);
      q[2]=__builtin_amdgcn_mfma_f32_16x16x32_bf16(a0,b2,q[2],0,0,0);
      q[3]=__builtin_amdgcn_mfma_f32_16x16x32_bf16(a0,b3,q[3],0,0,0);
    }
    #pragma unroll
    for (int nt=0;nt<4;nt++){
      int n = ng*64 + nt*16 + nl;
      #pragma unroll
      for (int r=0;r<4;r++)
        QbE[(size_t)(n0+quad*4+r)*HID + n] = f2b(q[nt][r]);
    }
    if (blk < N_LIGC/16){
      q[0]=zero4; q[1]=zero4; q[2]=zero4; q[3]=zero4;
      #pragma unroll 2
      for (int k0=0;k0<8;k0++){
        bf16x8 a0 = *(const bf16x8*)(sA + nl*520 + k0*32 + quad*8);
        const u16* wb = eWabN + ((size_t)(k0*16 + ng*4)*64 + lane)*8;
        bf16x8 b0 = *(const bf16x8*)(wb);
        bf16x8 b1 = *(const bf16x8*)(wb + 512);
        bf16x8 b2 = *(const bf16x8*)(wb + 1024);
        bf16x8 b3 = *(const bf16x8*)(wb + 1536);
        q[0]=__builtin_amdgcn_mfma_f32_16x16x32_bf16(a0,b0,q[0],0,0,0);
        q[1]=__builtin_amdgcn_mfma_f32_16x16x32_bf16(a0,b1,q[1],0,0,0);
        q[2]=__builtin_amdgcn_mfma_f32_16x16x32_bf16(a0,b2,q[2],0,0,0);
        q[3]=__builtin_amdgcn_mfma_f32_16x16x32_bf16(a0,b3,q[3],0,0,0);
      }
      #pragma unroll
      for (int nt=0;nt<4;nt++){
        int n = ng*64 + nt*16 + nl;
        #pragma unroll
        for (int r=0;r<4;r++)
          RE[(size_t)(n0+quad*4+r)*HID + n] = q[nt][r];
      }
    }
  }
  if (doOut && blk < N_LIGC/16 && ng < 2){
    int ntw = ng;
    f32x4 o = zero4;
    #pragma unroll 2
    for (int k0=0;k0<8;k0++){
      bf16x8 a = *(const bf16x8*)(sA + nl*520 + k0*32 + quad*8);
      bf16x8 b = *(const bf16x8*)(WoutP + ((size_t)(k0*2 + ntw)*64 + lane)*8);
      o = __builtin_amdgcn_mfma_f32_16x16x32_bf16(a,b,o,0,0,0);
    }
    int n = ntw*16 + nl;
    float bb = bout[n];
    #pragma unroll
    for (int r=0;r<4;r++){
      int m = quad*4 + r;
      outH[(size_t)(n0+m)*32 + n] = o[r] + bb;
    }
  }
}

// ---- coord combine (48 edges/block, grid 1024, single in-place LDS buffer) ----
__global__ __launch_bounds__(256) void k_comb_coord(
    const u16* __restrict__ Qb, const float* __restrict__ R,
    const float* __restrict__ xc, float* __restrict__ xn,
    const int* __restrict__ colIdx, const float* __restrict__ emb0,
    const u16* __restrict__ W1cP, const float* __restrict__ B1,
    const u16* __restrict__ W2p, const float* __restrict__ B2,
    const float* __restrict__ cW3,
    const float* __restrict__ posw, float* __restrict__ outX, int doOut, int l)
{
  __shared__ __align__(16) u16 sBuf[48*264];
  __shared__ __align__(16) u16 sEA[48*40];
  __shared__ float sR[256];
  __shared__ int sCol[48];
  __shared__ float sD[48];
  __shared__ float sCd[48*3];
  __shared__ float sS[48];
  __shared__ float sDot[48][4];

  int row = blockIdx.x, tid = threadIdx.x;
  int lane = tid & 63, ng = tid >> 6;
  int quad = lane >> 4, nl = lane & 15;

  if (tid < 48) sCol[tid] = colIdx[(size_t)row*KNN + tid];
  sR[tid] = R[(size_t)row*HID + tid];
  __syncthreads();
  for (int t = tid; t < 48*32; t += 256){
    int e = t >> 5, q = t & 31;
    uint4 v = ((const uint4*)(Qb + (size_t)sCol[e]*HID))[q];
    *(uint4*)(sBuf + e*264 + q*8) = v;
  }
  if (tid < 48){
    int cg = sCol[tid];
    float dx = xc[row*3+0]-xc[cg*3+0];
    float dy = xc[row*3+1]-xc[cg*3+1];
    float dz = xc[row*3+2]-xc[cg*3+2];
    float d = sqrtf(dx*dx+dy*dy+dz*dz + 1e-8f);
    sD[tid] = d;
    float rden = __builtin_amdgcn_rcpf(d + 1.0f);
    sCd[tid*3+0]=dx*rden; sCd[tid*3+1]=dy*rden; sCd[tid*3+2]=dz*rden;
    u16* ea = sEA + tid*40;
    #pragma unroll
    for (int i=0;i<12;i++) ea[12+i] = f2b_p(emb0[((size_t)row*KNN + tid)*12 + i]);
    #pragma unroll
    for (int i=24;i<32;i++) ea[i] = 0;
  }
  __syncthreads();
  for (int t=tid; t<288; t+=256){
    int e = t/6, i = t - 6*e;
    float fr = 0.41887903f * (float)(1 << (2*i));
    float x = sD[e]*fr;
    u16* ea = sEA + e*40;
    ea[i]   = f2b(__sinf(x));
    ea[6+i] = f2b(__cosf(x));
  }
  __syncthreads();

  f32x4 zero4 = {0.f,0.f,0.f,0.f};
  f32x4 acc[3][4];
  #pragma unroll
  for (int i=0;i<3;i++){ acc[i][0]=zero4; acc[i][1]=zero4; acc[i][2]=zero4; acc[i][3]=zero4; }
  {
    const u16* Wc = W1cP + (size_t)l*32*HID;
    const u16* wb = Wc + ((size_t)(ng*4)*64 + lane)*8;
    bf16x8 b0 = *(const bf16x8*)(wb);
    bf16x8 b1 = *(const bf16x8*)(wb + 512);
    bf16x8 b2 = *(const bf16x8*)(wb + 1024);
    bf16x8 b3 = *(const bf16x8*)(wb + 1536);
    bf16x8 a0 = *(const bf16x8*)(sEA + (0*16+nl)*40 + quad*8);
    bf16x8 a1 = *(const bf16x8*)(sEA + (1*16+nl)*40 + quad*8);
    bf16x8 a2 = *(const bf16x8*)(sEA + (2*16+nl)*40 + quad*8);
    acc[0][0]=__builtin_amdgcn_mfma_f32_16x16x32_bf16(a0,b0,acc[0][0],0,0,0);
    acc[0][1]=__builtin_amdgcn_mfma_f32_16x16x32_bf16(a0,b1,acc[0][1],0,0,0);
    acc[0][2]=__builtin_amdgcn_mfma_f32_16x16x32_bf16(a0,b2,acc[0][2],0,0,0);
    acc[0][3]=__builtin_amdgcn_mfma_f32_16x16x32_bf16(a0,b3,acc[0][3],0,0,0);
    acc[1][0]=__builtin_amdgcn_mfma_f32_16x16x32_bf16(a1,b0,acc[1][0],0,0,0);
    acc[1][1]=__builtin_amdgcn_mfma_f32_16x16x32_bf16(a1,b1,acc[1][1],0,0,0);
    acc[1][2]=__builtin_amdgcn_mfma_f32_16x16x32_bf16(a1,b2,acc[1][2],0,0,0);
    acc[1][3]=__builtin_amdgcn_mfma_f32_16x16x32_bf16(a1,b3,acc[1][3],0,0,0);
    acc[2][0]=__builtin_amdgcn_mfma_f32_16x16x32_bf16(a2,b0,acc[2][0],0,0,0);
    acc[2][1]=__builtin_amdgcn_mfma_f32_16x16x32_bf16(a2,b1,acc[2][1],0,0,0);
    acc[2][2]=__builtin_amdgcn_mfma_f32_16x16x32_bf16(a2,b2,acc[2][2],0,0,0);
    acc[2][3]=__builtin_amdgcn_mfma_f32_16x16x32_bf16(a2,b3,acc[2][3],0,0,0);
  }
  #pragma unroll
  for (int mt=0;mt<3;mt++)
  #pragma unroll
  for (int nt=0;nt<4;nt++){
    int n = ng*64 + nt*16 + nl;
    float bb = B1[l*HID + n] + sR[n];
    #pragma unroll
    for (int r=0;r<4;r++){
      int m = mt*16 + quad*4 + r;
      float v = acc[mt][nt][r] + bb + b2f(sBuf[m*264 + n]);
      sBuf[m*264 + n] = f2b(silu_f(v));
    }
  }
  __syncthreads();

  f32x4 acc2[3][4];
  #pragma unroll
  for (int i=0;i<3;i++){ acc2[i][0]=zero4; acc2[i][1]=zero4; acc2[i][2]=zero4; acc2[i][3]=zero4; }
  const u16* W2 = W2p + (size_t)l*HID*HID;
  #pragma unroll 2
  for (int k0=0;k0<8;k0++){
    bf16x8 a0 = *(const bf16x8*)(sBuf + (0*16+nl)*264 + k0*32 + quad*8);
    bf16x8 a1 = *(const bf16x8*)(sBuf + (1*16+nl)*264 + k0*32 + quad*8);
    bf16x8 a2 = *(const bf16x8*)(sBuf + (2*16+nl)*264 + k0*32 + quad*8);
    const u16* wb = W2 + ((size_t)(k0*16 + ng*4)*64 + lane)*8;
    bf16x8 b0 = *(const bf16x8*)(wb);
    bf16x8 b1 = *(const bf16x8*)(wb + 512);
    bf16x8 b2 = *(const bf16x8*)(wb + 1024);
    bf16x8 b3 = *(const bf16x8*)(wb + 1536);
    acc2[0][0]=__builtin_amdgcn_mfma_f32_16x16x32_bf16(a0,b0,acc2[0][0],0,0,0);
    acc2[0][1]=__builtin_amdgcn_mfma_f32_16x16x32_bf16(a0,b1,acc2[0][1],0,0,0);
    acc2[0][2]=__builtin_amdgcn_mfma_f32_16x16x32_bf16(a0,b2,acc2[0][2],0,0,0);
    acc2[0][3]=__builtin_amdgcn_mfma_f32_16x16x32_bf16(a0,b3,acc2[0][3],0,0,0);
    acc2[1][0]=__builtin_amdgcn_mfma_f32_16x16x32_bf16(a1,b0,acc2[1][0],0,0,0);
    acc2[1][1]=__builtin_amdgcn_mfma_f32_16x16x32_bf16(a1,b1,acc2[1][1],0,0,0);
    acc2[1][2]=__builtin_amdgcn_mfma_f32_16x16x32_bf16(a1,b2,acc2[1][2],0,0,0);
    acc2[1][3]=__builtin_amdgcn_mfma_f32_16x16x32_bf16(a1,b3,acc2[1][3],0,0,0);
    acc2[2][0]=__builtin_amdgcn_mfma_f32_16x16x32_bf16(a2,b0,acc2[2][0],0,0,0);
    acc2[2][1]=__builtin_amdgcn_mfma_f32_16x16x32_bf16(a2,b1,acc2[2][1],0,0,0);
    acc2[2][2]=__builtin_amdgcn_mfma_f32_16x16x32_bf16(a2,b2,acc2[2][2],0,0,0);
    acc2[2][3]=__builtin_amdgcn_mfma_f32_16x16x32_bf16(a2,b3,acc2[2][3],0,0,0);
  }
  __syncthreads();
  #pragma unroll
  for (int mt=0;mt<3;mt++)
  #pragma unroll
  for (int nt=0;nt<4;nt++){
    int n = ng*64 + nt*16 + nl;
    float bb = B2[l*HID + n];
    #pragma unroll
    for (int r=0;r<4;r++){
      int m = mt*16 + quad*4 + r;
      sBuf[m*264 + n] = f2b(silu_f(acc2[mt][nt][r] + bb));
    }
  }
  __syncthreads();
  if (tid < 192){
    int e = tid >> 2, qq = tid & 3;
    const unsigned int* rowp = (const unsigned int*)(sBuf + e*264 + qq*64);
    const float* wbase = cW3 + l*HID + qq*64;
    float s = 0.f;
    #pragma unroll 4
    for (int p0=0;p0<32;p0++){
      int p = (p0 + e + 8*qq) & 31;
      unsigned int v = rowp[p];
      s += b2f((u16)(v & 0xffffu))*wbase[2*p] + b2f((u16)(v >> 16))*wbase[2*p+1];
    }
    sDot[e][qq] = s;
  }
  __syncthreads();
  if (tid < 48) sS[tid] = sDot[tid][0]+sDot[tid][1]+sDot[tid][2]+sDot[tid][3];
  __syncthreads();
  if (tid < 3){
    float u = 0.f;
    #pragma unroll 4
    for (int e=0;e<48;e++) u += sCd[e*3+tid]*sS[e];
    float nv = xc[row*3+tid] + u*0.2f;
    xn[row*3+tid] = nv;
    if (doOut) outX[row*3+tid] = nv*posw[0];
  }
}

extern "C" void kernel_launch(void* const* d_in, const int* in_sizes, int n_in,
                              void* d_out, int out_size, void* d_ws, size_t ws_size,
                              hipStream_t stream)
{
  const float* protPos = (const float*)d_in[0];
  const int*   protEle = (const int*)d_in[1];
  const int*   protAA  = (const int*)d_in[2];
  const int*   protBB  = (const int*)d_in[3];
  const float* XtPos   = (const float*)d_in[4];
  const float* XtFeat  = (const float*)d_in[5];
  const int*   tArr    = (const int*)d_in[6];
  const float* WtTime  = (const float*)d_in[7];
  const float* Wele    = (const float*)d_in[8];
  const float* Waa     = (const float*)d_in[9];
  const float* Wbb     = (const float*)d_in[10];
  const float* Win     = (const float*)d_in[11];
  const float* bin     = (const float*)d_in[12];
  const float* Wout    = (const float*)d_in[13];
  const float* bout    = (const float*)d_in[14];
  const float* eW1     = (const float*)d_in[15];
  const float* eB1     = (const float*)d_in[16];
  const float* eW2     = (const float*)d_in[17];
  const float* eB2     = (const float*)d_in[18];
  const float* attW    = (const float*)d_in[19];
  const float* attB    = (const float*)d_in[20];
  const float* nW1     = (const float*)d_in[21];
  const float* nB1     = (const float*)d_in[22];
  const float* nW2     = (const float*)d_in[23];
  const float* nB2     = (const float*)d_in[24];
  const float* cW1     = (const float*)d_in[25];
  const float* cB1     = (const float*)d_in[26];
  const float* cW2     = (const float*)d_in[27];
  const float* cB2     = (const float*)d_in[28];
  const float* cW3     = (const float*)d_in[29];
  const float* posw    = (const float*)d_in[30];

  float* fp = (float*)d_ws;
  float* X0   = fp;               fp += NTOT*3;
  float* X1   = fp;               fp += NTOT*3;
  float* h    = fp;               fp += (size_t)NTOT*HID;
  float* emb0 = fp;               fp += (size_t)ETOT*12;
  float* RC   = fp;               fp += (size_t)N_LIGC*HID;
  float* RE   = fp;               fp += (size_t)N_LIGC*HID;
  int*   col  = (int*)fp;         fp += ETOT;
  u16*   up   = (u16*)fp;
  u16* h_bf   = up;               up += (size_t)NTOT*HID;
  u16* agg_bf = up;               up += (size_t)N_LIGC*HID;
  u16* QbE    = up;               up += (size_t)NTOT*HID;
  u16* QbC    = up;               up += (size_t)NTOT*HID;
  u16* eW1abP = up;               up += (size_t)DEPTHC*512*HID;
  u16* eW1cP  = up;               up += (size_t)DEPTHC*32*HID;
  u16* eW2p   = up;               up += (size_t)DEPTHC*HID*HID;
  u16* nW1p   = up;               up += (size_t)DEPTHC*512*HID;
  u16* nW2p   = up;               up += (size_t)DEPTHC*HID*HID;
  u16* cW1abP = up;               up += (size_t)DEPTHC*512*HID;
  u16* cW1cP  = up;               up += (size_t)DEPTHC*32*HID;
  u16* cW2p   = up;               up += (size_t)DEPTHC*HID*HID;
  u16* WoutP  = up;               up += (size_t)256*32;

  k_packall<<<1484,256,0,stream>>>(eW1,eW2,nW1,nW2,cW1,cW2,Wout,
      eW1abP,eW1cP,eW2p,nW1p,nW2p,cW1abP,cW1cP,cW2p,WoutP);
  k_embed_hinit<<<NTOT/8,256,0,stream>>>(protPos,protEle,protAA,protBB,XtPos,XtFeat,
      tArr,WtTime,Wele,Waa,Wbb,Win,bin,X0,X1,h,h_bf);
  k_knn<<<N_LIGC,256,0,stream>>>(X0,col,emb0);
  k_pq<<<NTOT/32,256,0,stream>>>(h_bf,eW1abP,RE,QbE,0);

  float* xc = X0; float* xn = X1;
  float* outF = (float*)d_out;
  for (int l=0;l<DEPTHC;l++){
    int doE = (l<DEPTHC-1)?1:0;
    int doOut = (l==DEPTHC-1)?1:0;
    const u16* eNext = eW1abP + (size_t)((l+1)%DEPTHC)*512*HID;
    k_comb_edge<<<N_LIGC,256,0,stream>>>(QbE,RE,xc,col,emb0,eW1cP,eB1,eW2p,eB2,
        attW,attB,agg_bf,l);
    k_node<<<NTOT/16,256,0,stream>>>(h,h_bf,agg_bf,nW1p,nB1,nW2p,nB2,
        cW1abP,QbC,RC, eNext,QbE,RE,doE,
        WoutP,bout, outF+3072, doOut, l);
    k_comb_coord<<<N_LIGC,256,0,stream>>>(QbC,RC,xc,xn,col,emb0,cW1cP,cB1,cW2p,cB2,cW3,
        posw, outF, doOut, l);
    float* t2=xc; xc=xn; xn=t2;
  }
}

// Round 14
// 614.519 us; speedup vs baseline: 1.0267x; 1.0267x over previous
//
#include <hip/hip_runtime.h>
#include <hip/hip_bf16.h>
#include <math.h>

#define N_LIGC 1024
#define NTOT 9216
#define KNN 48
#define HID 256
#define DEPTHC 5
#define ETOT (N_LIGC*KNN)
#define KBINS 4096

typedef unsigned short u16;
typedef __attribute__((ext_vector_type(8))) short bf16x8;
typedef __attribute__((ext_vector_type(4))) float f32x4;

__device__ __forceinline__ float freq_f(int i){
  double p = (double)(1 << (2*i));
  return (float)((2.0*3.14159265358979323846)*p/15.0);
}
// fast silu/sigmoid: native exp + single v_rcp_f32 (avoids IEEE div sequence)
__device__ __forceinline__ float silu_f(float v){
  return v*__builtin_amdgcn_rcpf(1.0f+__expf(-v));
}
__device__ __forceinline__ float sigm_f(float v){
  return __builtin_amdgcn_rcpf(1.0f+__expf(-v));
}
// branchless RNE float->bf16
__device__ __forceinline__ u16 f2b(float f){
  unsigned int u = __float_as_uint(f);
  return (u16)((u + 0x7fffu + ((u>>16)&1u)) >> 16);
}
__device__ __forceinline__ float b2f(u16 u){
  union { unsigned int i; float f; } c; c.i = ((unsigned int)u)<<16; return c.f;
}
// precise RNE (for weight packing, matches __float2bfloat16)
__device__ __forceinline__ u16 f2b_p(float f){
  union { __hip_bfloat16 h; u16 u; } c; c.h = __float2bfloat16(f); return c.u;
}

// ---- pack fp32 [L][srcK][N] rows [kOff,kOff+Keff) -> bf16 B-frag layout
__device__ __forceinline__ void pack_one(const float* __restrict__ src,
    u16* __restrict__ dst, int srcK, int kOff, int Keff, int Kp, int N, int idx)
{
  int lane = idx & 63;
  int rest = idx >> 6;
  int Nt = N >> 4;
  int n0 = rest % Nt;
  int rest2 = rest / Nt;
  int Kt = Kp >> 5;
  int k0 = rest2 % Kt;
  int layer = rest2 / Kt;
  int kq = lane >> 4, nl = lane & 15;
  int kb = k0*32 + kq*8, n = n0*16 + nl;
  u16 o[8];
  #pragma unroll
  for (int j=0;j<8;j++){
    int k = kb + j;
    float v = (k < Keff) ? src[((size_t)layer*srcK + kOff + k)*N + n] : 0.f;
    o[j] = f2b_p(v);
  }
  *(uint4*)(dst + (size_t)idx*8) = *(uint4*)o;
}

__global__ __launch_bounds__(256) void k_packall(
    const float* eW1, const float* eW2, const float* nW1, const float* nW2,
    const float* cW1, const float* cW2, const float* Wout,
    u16* eW1abP, u16* eW1cP, u16* eW2p, u16* nW1p, u16* nW2p,
    u16* cW1abP, u16* cW1cP, u16* cW2p, u16* WoutP)
{
  int idx = blockIdx.x*256 + threadIdx.x;
  if (idx < 81920){ pack_one(eW1, eW1abP, 536, 0,   512, 512, 256, idx); return; } idx -= 81920;
  if (idx < 5120 ){ pack_one(eW1, eW1cP,  536, 512, 24,  32,  256, idx); return; } idx -= 5120;
  if (idx < 40960){ pack_one(eW2, eW2p,   256, 0,   256, 256, 256, idx); return; } idx -= 40960;
  if (idx < 81920){ pack_one(nW1, nW1p,   512, 0,   512, 512, 256, idx); return; } idx -= 81920;
  if (idx < 40960){ pack_one(nW2, nW2p,   256, 0,   256, 256, 256, idx); return; } idx -= 40960;
  if (idx < 81920){ pack_one(cW1, cW1abP, 536, 0,   512, 512, 256, idx); return; } idx -= 81920;
  if (idx < 5120 ){ pack_one(cW1, cW1cP,  536, 512, 24,  32,  256, idx); return; } idx -= 5120;
  if (idx < 40960){ pack_one(cW2, cW2p,   256, 0,   256, 256, 256, idx); return; } idx -= 40960;
  if (idx < 1024 ){ pack_one(Wout, WoutP, 256, 0,   256, 256, 32,  idx); return; }
}

// ---- fused embed + h-init ----
__global__ __launch_bounds__(256) void k_embed_hinit(
    const float* __restrict__ protPos, const int* __restrict__ protEle,
    const int* __restrict__ protAA, const int* __restrict__ protBB,
    const float* __restrict__ XtPos, const float* __restrict__ XtFeat,
    const int* __restrict__ tArr, const float* __restrict__ WtTime,
    const float* __restrict__ Wele, const float* __restrict__ Waa,
    const float* __restrict__ Wbb,
    const float* __restrict__ Win, const float* __restrict__ bin,
    float* __restrict__ X0, float* __restrict__ X1,
    float* __restrict__ h, u16* __restrict__ h_bf)
{
  __shared__ float sF[8*40];
  int blk=blockIdx.x, tid=threadIdx.x;
  int n0=blk*8;
  for (int x=tid; x<344; x+=256){
    if (x < 320){
      int n = x/40, k = x%40;
      int node = n0+n;
      float v;
      if (node < N_LIGC){
        if (k < 32) v = XtFeat[node*32+k];
        else        v = WtTime[tArr[node]*8 + (k-32)];
      } else {
        int p = node - N_LIGC;
        if (k < 16)      v = Wele[protEle[p]*16 + k];
        else if (k < 32) v = Waa[protAA[p]*16 + (k-16)];
        else             v = Wbb[protBB[p]*8 + (k-32)];
      }
      sF[n*40+k] = v;
    } else {
      int r = x-320; int n = r/3, c = r%3;
      int node = n0+n;
      float v = (node < N_LIGC) ? XtPos[node*3+c] : protPos[(node-N_LIGC)*3+c];
      X0[node*3+c] = v; X1[node*3+c] = v;
    }
  }
  __syncthreads();
  float acc[8];
  float b=bin[tid];
  #pragma unroll
  for (int n=0;n<8;n++) acc[n]=b;
  for (int k=0;k<40;k++){
    float w=Win[k*HID+tid];
    #pragma unroll
    for (int n=0;n<8;n++) acc[n]+=sF[n*40+k]*w;
  }
  #pragma unroll
  for (int n=0;n<8;n++){
    h[(size_t)(n0+n)*HID+tid]=acc[n];
    h_bf[(size_t)(n0+n)*HID+tid]=f2b_p(acc[n]);
  }
}

// ---- KNN: radix-histogram top-K ----
__global__ __launch_bounds__(256) void k_knn(const float* __restrict__ X,
    int* __restrict__ col, float* __restrict__ emb0)
{
  __shared__ unsigned int hist[KBINS];
  __shared__ unsigned int part[256];
  __shared__ float selD[KNN];
  __shared__ int   candI[512];
  __shared__ float candV[512];
  __shared__ int sB, sCless, sNeed, sNsel, sNcand;
  int b = blockIdx.x, tid = threadIdx.x;
  for (int i=tid;i<KBINS;i+=256) hist[i]=0u;
  if (tid==0){ sNsel=0; sNcand=0; }
  float px = X[b*3+0], py = X[b*3+1], pz = X[b*3+2];
  __syncthreads();
  #pragma unroll 4
  for (int j=0;j<36;j++){
    int i = tid + 256*j;
    float dx = __fsub_rn(px, X[i*3+0]);
    float dy = __fsub_rn(py, X[i*3+1]);
    float dz = __fsub_rn(pz, X[i*3+2]);
    float d2 = __fadd_rn(__fadd_rn(__fmul_rn(dx,dx),__fmul_rn(dy,dy)),__fmul_rn(dz,dz));
    if (i==b) d2 = INFINITY;
    unsigned key = __float_as_uint(d2) >> 19;
    atomicAdd(&hist[key], 1u);
  }
  __syncthreads();
  {
    unsigned s=0;
    #pragma unroll 4
    for (int k=0;k<16;k++) s += hist[tid*16+k];
    part[tid]=s;
  }
  __syncthreads();
  if (tid==0){
    unsigned c=0; int chunk=0;
    for (int t=0;t<256;t++){
      if (c + part[t] >= (unsigned)KNN){ chunk=t; break; }
      c += part[t];
    }
    int bin = chunk*16;
    for (;;bin++){
      unsigned hh = hist[bin];
      if (c + hh >= (unsigned)KNN) break;
      c += hh;
    }
    sB = bin; sCless = (int)c; sNeed = KNN - (int)c;
  }
  __syncthreads();
  int B = sB;
  #pragma unroll 4
  for (int j=0;j<36;j++){
    int i = tid + 256*j;
    float dx = __fsub_rn(px, X[i*3+0]);
    float dy = __fsub_rn(py, X[i*3+1]);
    float dz = __fsub_rn(pz, X[i*3+2]);
    float d2 = __fadd_rn(__fadd_rn(__fmul_rn(dx,dx),__fmul_rn(dy,dy)),__fmul_rn(dz,dz));
    if (i==b) d2 = INFINITY;
    int key = (int)(__float_as_uint(d2) >> 19);
    if (key < B){
      int p = atomicAdd(&sNsel, 1);
      col[b*KNN+p] = i; selD[p] = d2;
    } else if (key == B){
      int c = atomicAdd(&sNcand, 1);
      if (c < 512){ candI[c] = i; candV[c] = d2; }
    }
  }
  __syncthreads();
  if (tid < 64){
    int m = sNcand; if (m > 512) m = 512;
    int need = sNeed, base = sCless;
    float cv[8]; int ci[8];
    #pragma unroll
    for (int k=0;k<8;k++){
      int c = tid + 64*k;
      if (c < m){ ci[k]=candI[c]; cv[k]=candV[c]; }
      else      { ci[k]=0x7fffffff; cv[k]=INFINITY; }
    }
    for (int it=0; it<need; it++){
      float bv=INFINITY; int bi=0x7fffffff; int bk=0;
      #pragma unroll
      for (int k=0;k<8;k++){
        if (cv[k]<bv || (cv[k]==bv && ci[k]<bi)){ bv=cv[k]; bi=ci[k]; bk=k; }
      }
      int bslot = tid + 64*bk;
      #pragma unroll
      for (int off=32; off>=1; off>>=1){
        float ov = __shfl_down(bv, off);
        int   oi = __shfl_down(bi, off);
        int   os = __shfl_down(bslot, off);
        if (ov < bv || (ov==bv && oi<bi)){ bv=ov; bi=oi; bslot=os; }
      }
      int wslot = __shfl(bslot, 0);
      if (tid==0){ col[b*KNN+base+it]=bi; selD[base+it]=bv; }
      if ((wslot & 63) == tid) cv[wslot >> 6] = INFINITY;
    }
  }
  __syncthreads();
  if (tid < KNN){
    float d = sqrtf(selD[tid] + 1e-8f);
    int base = (b*KNN+tid)*12;
    #pragma unroll
    for (int i=0;i<6;i++){
      float fr = freq_f(i);
      emb0[base+i]   = sinf(d*fr);
      emb0[base+6+i] = cosf(d*fr);
    }
  }
}

// ---- k_pq: initial Q/R for layer 0 edge stage ----
__global__ __launch_bounds__(256) void k_pq(const u16* __restrict__ h_bf,
    const u16* __restrict__ Wab, float* __restrict__ R, u16* __restrict__ Qb, int l)
{
  __shared__ __align__(16) u16 sA[32*264];
  int blk=blockIdx.x, tid=threadIdx.x;
  int lane=tid&63, ng=tid>>6, quad=lane>>4, nl=lane&15;
  for (int t=tid; t<32*32; t+=256){
    int i=t>>5, q=t&31;
    uint4 v = ((const uint4*)(h_bf + (size_t)(blk*32+i)*HID))[q];
    *(uint4*)(sA + i*264 + q*8) = v;
  }
  __syncthreads();
  const u16* Wl = Wab + (size_t)l*512*HID;
  f32x4 zero4 = {0.f,0.f,0.f,0.f};
  f32x4 aQ[2][4];
  #pragma unroll
  for (int i=0;i<2;i++){ aQ[i][0]=zero4; aQ[i][1]=zero4; aQ[i][2]=zero4; aQ[i][3]=zero4; }
  #pragma unroll 2
  for (int k0=0;k0<8;k0++){
    bf16x8 a0 = *(const bf16x8*)(sA + (0*16+nl)*264 + k0*32 + quad*8);
    bf16x8 a1 = *(const bf16x8*)(sA + (1*16+nl)*264 + k0*32 + quad*8);
    const u16* wb = Wl + ((size_t)((k0+8)*16 + ng*4)*64 + lane)*8;
    bf16x8 b0 = *(const bf16x8*)(wb);
    bf16x8 b1 = *(const bf16x8*)(wb + 512);
    bf16x8 b2 = *(const bf16x8*)(wb + 1024);
    bf16x8 b3 = *(const bf16x8*)(wb + 1536);
    aQ[0][0]=__builtin_amdgcn_mfma_f32_16x16x32_bf16(a0,b0,aQ[0][0],0,0,0);
    aQ[0][1]=__builtin_amdgcn_mfma_f32_16x16x32_bf16(a0,b1,aQ[0][1],0,0,0);
    aQ[0][2]=__builtin_amdgcn_mfma_f32_16x16x32_bf16(a0,b2,aQ[0][2],0,0,0);
    aQ[0][3]=__builtin_amdgcn_mfma_f32_16x16x32_bf16(a0,b3,aQ[0][3],0,0,0);
    aQ[1][0]=__builtin_amdgcn_mfma_f32_16x16x32_bf16(a1,b0,aQ[1][0],0,0,0);
    aQ[1][1]=__builtin_amdgcn_mfma_f32_16x16x32_bf16(a1,b1,aQ[1][1],0,0,0);
    aQ[1][2]=__builtin_amdgcn_mfma_f32_16x16x32_bf16(a1,b2,aQ[1][2],0,0,0);
    aQ[1][3]=__builtin_amdgcn_mfma_f32_16x16x32_bf16(a1,b3,aQ[1][3],0,0,0);
  }
  #pragma unroll
  for (int mt=0;mt<2;mt++)
  #pragma unroll
  for (int nt=0;nt<4;nt++){
    int n = ng*64 + nt*16 + nl;
    #pragma unroll
    for (int r=0;r<4;r++){
      int node = blk*32 + mt*16 + quad*4 + r;
      Qb[(size_t)node*HID + n] = f2b(aQ[mt][nt][r]);
    }
  }
  if (blk < 32){
    f32x4 aR[2][4];
    #pragma unroll
    for (int i=0;i<2;i++){ aR[i][0]=zero4; aR[i][1]=zero4; aR[i][2]=zero4; aR[i][3]=zero4; }
    #pragma unroll 2
    for (int k0=0;k0<8;k0++){
      bf16x8 a0 = *(const bf16x8*)(sA + (0*16+nl)*264 + k0*32 + quad*8);
      bf16x8 a1 = *(const bf16x8*)(sA + (1*16+nl)*264 + k0*32 + quad*8);
      const u16* wb = Wl + ((size_t)(k0*16 + ng*4)*64 + lane)*8;
      bf16x8 b0 = *(const bf16x8*)(wb);
      bf16x8 b1 = *(const bf16x8*)(wb + 512);
      bf16x8 b2 = *(const bf16x8*)(wb + 1024);
      bf16x8 b3 = *(const bf16x8*)(wb + 1536);
      aR[0][0]=__builtin_amdgcn_mfma_f32_16x16x32_bf16(a0,b0,aR[0][0],0,0,0);
      aR[0][1]=__builtin_amdgcn_mfma_f32_16x16x32_bf16(a0,b1,aR[0][1],0,0,0);
      aR[0][2]=__builtin_amdgcn_mfma_f32_16x16x32_bf16(a0,b2,aR[0][2],0,0,0);
      aR[0][3]=__builtin_amdgcn_mfma_f32_16x16x32_bf16(a0,b3,aR[0][3],0,0,0);
      aR[1][0]=__builtin_amdgcn_mfma_f32_16x16x32_bf16(a1,b0,aR[1][0],0,0,0);
      aR[1][1]=__builtin_amdgcn_mfma_f32_16x16x32_bf16(a1,b1,aR[1][1],0,0,0);
      aR[1][2]=__builtin_amdgcn_mfma_f32_16x16x32_bf16(a1,b2,aR[1][2],0,0,0);
      aR[1][3]=__builtin_amdgcn_mfma_f32_16x16x32_bf16(a1,b3,aR[1][3],0,0,0);
    }
    #pragma unroll
    for (int mt=0;mt<2;mt++)
    #pragma unroll
    for (int nt=0;nt<4;nt++){
      int n = ng*64 + nt*16 + nl;
      #pragma unroll
      for (int r=0;r<4;r++){
        int node = blk*32 + mt*16 + quad*4 + r;
        R[(size_t)node*HID + n] = aR[mt][nt][r];
      }
    }
  }
}

// ---- edge combine (48 edges/block, grid 1024) ----
__global__ __launch_bounds__(256) void k_comb_edge(
    const u16* __restrict__ Qb, const float* __restrict__ R,
    const float* __restrict__ xc,
    const int* __restrict__ colIdx, const float* __restrict__ emb0,
    const u16* __restrict__ W1cP, const float* __restrict__ B1,
    const u16* __restrict__ W2p, const float* __restrict__ B2,
    const float* __restrict__ attW, const float* __restrict__ attB,
    u16* __restrict__ agg_bf, int l)
{
  __shared__ __align__(16) u16 sQ[48*264];
  __shared__ __align__(16) u16 sM1[48*264];
  __shared__ float sR[256];
  __shared__ int sCol[48];
  __shared__ float sD[48];
  __shared__ float sSig[48];
  __shared__ float sDot[48][4];
  u16* sM2 = sQ;
  u16* sEA = sM1;   // alias: ea staged in sM1 region, consumed by GEMM1, then overwritten

  int row = blockIdx.x, tid = threadIdx.x;
  int lane = tid & 63, ng = tid >> 6;
  int quad = lane >> 4, nl = lane & 15;

  if (tid < 48) sCol[tid] = colIdx[(size_t)row*KNN + tid];
  sR[tid] = R[(size_t)row*HID + tid];
  __syncthreads();
  for (int t = tid; t < 48*32; t += 256){
    int e = t >> 5, q = t & 31;
    uint4 v = ((const uint4*)(Qb + (size_t)sCol[e]*HID))[q];
    *(uint4*)(sQ + e*264 + q*8) = v;
  }
  if (tid < 48){
    int cg = sCol[tid];
    float dx = xc[row*3+0]-xc[cg*3+0];
    float dy = xc[row*3+1]-xc[cg*3+1];
    float dz = xc[row*3+2]-xc[cg*3+2];
    float d = sqrtf(dx*dx+dy*dy+dz*dz + 1e-8f);
    sD[tid] = d;
    u16* ea = sEA + tid*40;
    #pragma unroll
    for (int i=0;i<12;i++) ea[12+i] = f2b_p(emb0[((size_t)row*KNN + tid)*12 + i]);
    #pragma unroll
    for (int i=24;i<32;i++) ea[i] = 0;
  }
  __syncthreads();
  for (int t=tid; t<288; t+=256){
    int e = t/6, i = t - 6*e;
    float fr = 0.41887903f * (float)(1 << (2*i));
    float x = sD[e]*fr;
    u16* ea = sEA + e*40;
    ea[i]   = f2b(__sinf(x));
    ea[6+i] = f2b(__cosf(x));
  }
  __syncthreads();

  f32x4 zero4 = {0.f,0.f,0.f,0.f};
  f32x4 acc[3][4];
  #pragma unroll
  for (int i=0;i<3;i++){ acc[i][0]=zero4; acc[i][1]=zero4; acc[i][2]=zero4; acc[i][3]=zero4; }
  {
    const u16* Wc = W1cP + (size_t)l*32*HID;
    const u16* wb = Wc + ((size_t)(ng*4)*64 + lane)*8;
    bf16x8 b0 = *(const bf16x8*)(wb);
    bf16x8 b1 = *(const bf16x8*)(wb + 512);
    bf16x8 b2 = *(const bf16x8*)(wb + 1024);
    bf16x8 b3 = *(const bf16x8*)(wb + 1536);
    bf16x8 a0 = *(const bf16x8*)(sEA + (0*16+nl)*40 + quad*8);
    bf16x8 a1 = *(const bf16x8*)(sEA + (1*16+nl)*40 + quad*8);
    bf16x8 a2 = *(const bf16x8*)(sEA + (2*16+nl)*40 + quad*8);
    acc[0][0]=__builtin_amdgcn_mfma_f32_16x16x32_bf16(a0,b0,acc[0][0],0,0,0);
    acc[0][1]=__builtin_amdgcn_mfma_f32_16x16x32_bf16(a0,b1,acc[0][1],0,0,0);
    acc[0][2]=__builtin_amdgcn_mfma_f32_16x16x32_bf16(a0,b2,acc[0][2],0,0,0);
    acc[0][3]=__builtin_amdgcn_mfma_f32_16x16x32_bf16(a0,b3,acc[0][3],0,0,0);
    acc[1][0]=__builtin_amdgcn_mfma_f32_16x16x32_bf16(a1,b0,acc[1][0],0,0,0);
    acc[1][1]=__builtin_amdgcn_mfma_f32_16x16x32_bf16(a1,b1,acc[1][1],0,0,0);
    acc[1][2]=__builtin_amdgcn_mfma_f32_16x16x32_bf16(a1,b2,acc[1][2],0,0,0);
    acc[1][3]=__builtin_amdgcn_mfma_f32_16x16x32_bf16(a1,b3,acc[1][3],0,0,0);
    acc[2][0]=__builtin_amdgcn_mfma_f32_16x16x32_bf16(a2,b0,acc[2][0],0,0,0);
    acc[2][1]=__builtin_amdgcn_mfma_f32_16x16x32_bf16(a2,b1,acc[2][1],0,0,0);
    acc[2][2]=__builtin_amdgcn_mfma_f32_16x16x32_bf16(a2,b2,acc[2][2],0,0,0);
    acc[2][3]=__builtin_amdgcn_mfma_f32_16x16x32_bf16(a2,b3,acc[2][3],0,0,0);
  }
  __syncthreads();
  #pragma unroll
  for (int mt=0;mt<3;mt++)
  #pragma unroll
  for (int nt=0;nt<4;nt++){
    int n = ng*64 + nt*16 + nl;
    float bb = B1[l*HID + n] + sR[n];
    #pragma unroll
    for (int r=0;r<4;r++){
      int m = mt*16 + quad*4 + r;
      float v = acc[mt][nt][r] + bb + b2f(sQ[m*264 + n]);
      sM1[m*264 + n] = f2b(silu_f(v));
    }
  }
  __syncthreads();

  f32x4 acc2[3][4];
  #pragma unroll
  for (int i=0;i<3;i++){ acc2[i][0]=zero4; acc2[i][1]=zero4; acc2[i][2]=zero4; acc2[i][3]=zero4; }
  const u16* W2 = W2p + (size_t)l*HID*HID;
  #pragma unroll 2
  for (int k0=0;k0<8;k0++){
    bf16x8 a0 = *(const bf16x8*)(sM1 + (0*16+nl)*264 + k0*32 + quad*8);
    bf16x8 a1 = *(const bf16x8*)(sM1 + (1*16+nl)*264 + k0*32 + quad*8);
    bf16x8 a2 = *(const bf16x8*)(sM1 + (2*16+nl)*264 + k0*32 + quad*8);
    const u16* wb = W2 + ((size_t)(k0*16 + ng*4)*64 + lane)*8;
    bf16x8 b0 = *(const bf16x8*)(wb);
    bf16x8 b1 = *(const bf16x8*)(wb + 512);
    bf16x8 b2 = *(const bf16x8*)(wb + 1024);
    bf16x8 b3 = *(const bf16x8*)(wb + 1536);
    acc2[0][0]=__builtin_amdgcn_mfma_f32_16x16x32_bf16(a0,b0,acc2[0][0],0,0,0);
    acc2[0][1]=__builtin_amdgcn_mfma_f32_16x16x32_bf16(a0,b1,acc2[0][1],0,0,0);
    acc2[0][2]=__builtin_amdgcn_mfma_f32_16x16x32_bf16(a0,b2,acc2[0][2],0,0,0);
    acc2[0][3]=__builtin_amdgcn_mfma_f32_16x16x32_bf16(a0,b3,acc2[0][3],0,0,0);
    acc2[1][0]=__builtin_amdgcn_mfma_f32_16x16x32_bf16(a1,b0,acc2[1][0],0,0,0);
    acc2[1][1]=__builtin_amdgcn_mfma_f32_16x16x32_bf16(a1,b1,acc2[1][1],0,0,0);
    acc2[1][2]=__builtin_amdgcn_mfma_f32_16x16x32_bf16(a1,b2,acc2[1][2],0,0,0);
    acc2[1][3]=__builtin_amdgcn_mfma_f32_16x16x32_bf16(a1,b3,acc2[1][3],0,0,0);
    acc2[2][0]=__builtin_amdgcn_mfma_f32_16x16x32_bf16(a2,b0,acc2[2][0],0,0,0);
    acc2[2][1]=__builtin_amdgcn_mfma_f32_16x16x32_bf16(a2,b1,acc2[2][1],0,0,0);
    acc2[2][2]=__builtin_amdgcn_mfma_f32_16x16x32_bf16(a2,b2,acc2[2][2],0,0,0);
    acc2[2][3]=__builtin_amdgcn_mfma_f32_16x16x32_bf16(a2,b3,acc2[2][3],0,0,0);
  }
  #pragma unroll
  for (int mt=0;mt<3;mt++)
  #pragma unroll
  for (int nt=0;nt<4;nt++){
    int n = ng*64 + nt*16 + nl;
    float bb = B2[l*HID + n];
    #pragma unroll
    for (int r=0;r<4;r++){
      int m = mt*16 + quad*4 + r;
      sM2[m*264 + n] = f2b(silu_f(acc2[mt][nt][r] + bb));
    }
  }
  __syncthreads();
  if (tid < 192){
    int e = tid >> 2, qq = tid & 3;
    const unsigned int* rowp = (const unsigned int*)(sM2 + e*264 + qq*64);
    const float* wbase = attW + l*HID + qq*64;
    float s = 0.f;
    #pragma unroll 4
    for (int p0=0;p0<32;p0++){
      int p = (p0 + e + 8*qq) & 31;
      unsigned int v = rowp[p];
      s += b2f((u16)(v & 0xffffu))*wbase[2*p] + b2f((u16)(v >> 16))*wbase[2*p+1];
    }
    sDot[e][qq] = s;
  }
  __syncthreads();
  if (tid < 48){
    float s = sDot[tid][0]+sDot[tid][1]+sDot[tid][2]+sDot[tid][3] + attB[l];
    sSig[tid] = sigm_f(s);
  }
  __syncthreads();
  {
    float a = 0.f;
    #pragma unroll 4
    for (int e=0;e<48;e++) a += b2f(sM2[e*264 + tid])*sSig[e];
    agg_bf[(size_t)row*HID + tid] = f2b(a*0.2f);
  }
}

// ---- node MLP + residual + QC/RC + QE/RE + final outh (32 nodes/block) ----
__global__ __launch_bounds__(256) void k_node(
    float* __restrict__ h, u16* __restrict__ h_bf,
    const u16* __restrict__ agg_bf,
    const u16* __restrict__ W1p, const float* __restrict__ B1,
    const u16* __restrict__ W2p, const float* __restrict__ B2,
    const u16* __restrict__ cWab, u16* __restrict__ QbC, float* __restrict__ RC,
    const u16* __restrict__ eWabN, u16* __restrict__ QbE, float* __restrict__ RE, int doE,
    const u16* __restrict__ WoutP, const float* __restrict__ bout,
    float* __restrict__ outH, int doOut, int l)
{
  __shared__ __align__(16) u16 sA[32*520];
  __shared__ __align__(16) u16 sU[32*264];
  u16* sH = sA;
  int blk=blockIdx.x, tid=threadIdx.x;
  int lane=tid&63, wv=tid>>6, quad=lane>>4, nl=lane&15;
  for (int t=tid; t<32*64; t+=256){
    int i=t>>6, q=t&63;
    int node = blk*32+i;
    uint4 v;
    if (q<32) v = ((const uint4*)(h_bf + (size_t)node*HID))[q];
    else if (node < N_LIGC) v = ((const uint4*)(agg_bf + (size_t)node*HID))[q-32];
    else { v.x=0u; v.y=0u; v.z=0u; v.w=0u; }
    *(uint4*)(sA + i*520 + q*8) = v;
  }
  __syncthreads();
  f32x4 zero4 = {0.f,0.f,0.f,0.f};
  f32x4 acc[2][4];
  #pragma unroll
  for (int i=0;i<2;i++){ acc[i][0]=zero4; acc[i][1]=zero4; acc[i][2]=zero4; acc[i][3]=zero4; }
  const u16* Wp = W1p + (size_t)l*512*HID;
  #pragma unroll 2
  for (int k0=0;k0<16;k0++){
    bf16x8 a0 = *(const bf16x8*)(sA + (0*16+nl)*520 + k0*32 + quad*8);
    bf16x8 a1 = *(const bf16x8*)(sA + (1*16+nl)*520 + k0*32 + quad*8);
    const u16* wb = Wp + ((size_t)(k0*16 + wv*4)*64 + lane)*8;
    bf16x8 b0 = *(const bf16x8*)(wb);
    bf16x8 b1 = *(const bf16x8*)(wb + 512);
    bf16x8 b2 = *(const bf16x8*)(wb + 1024);
    bf16x8 b3 = *(const bf16x8*)(wb + 1536);
    acc[0][0]=__builtin_amdgcn_mfma_f32_16x16x32_bf16(a0,b0,acc[0][0],0,0,0);
    acc[0][1]=__builtin_amdgcn_mfma_f32_16x16x32_bf16(a0,b1,acc[0][1],0,0,0);
    acc[0][2]=__builtin_amdgcn_mfma_f32_16x16x32_bf16(a0,b2,acc[0][2],0,0,0);
    acc[0][3]=__builtin_amdgcn_mfma_f32_16x16x32_bf16(a0,b3,acc[0][3],0,0,0);
    acc[1][0]=__builtin_amdgcn_mfma_f32_16x16x32_bf16(a1,b0,acc[1][0],0,0,0);
    acc[1][1]=__builtin_amdgcn_mfma_f32_16x16x32_bf16(a1,b1,acc[1][1],0,0,0);
    acc[1][2]=__builtin_amdgcn_mfma_f32_16x16x32_bf16(a1,b2,acc[1][2],0,0,0);
    acc[1][3]=__builtin_amdgcn_mfma_f32_16x16x32_bf16(a1,b3,acc[1][3],0,0,0);
  }
  #pragma unroll
  for (int mt=0;mt<2;mt++)
  #pragma unroll
  for (int nt=0;nt<4;nt++){
    int n = wv*64 + nt*16 + nl;
    float bb = B1[l*HID + n];
    #pragma unroll
    for (int r=0;r<4;r++){
      int m = mt*16 + quad*4 + r;
      sU[m*264 + n] = f2b(silu_f(acc[mt][nt][r] + bb));
    }
  }
  __syncthreads();
  f32x4 acc2[2][4];
  #pragma unroll
  for (int i=0;i<2;i++){ acc2[i][0]=zero4; acc2[i][1]=zero4; acc2[i][2]=zero4; acc2[i][3]=zero4; }
  const u16* W2 = W2p + (size_t)l*HID*HID;
  #pragma unroll 2
  for (int k0=0;k0<8;k0++){
    bf16x8 a0 = *(const bf16x8*)(sU + (0*16+nl)*264 + k0*32 + quad*8);
    bf16x8 a1 = *(const bf16x8*)(sU + (1*16+nl)*264 + k0*32 + quad*8);
    const u16* wb = W2 + ((size_t)(k0*16 + wv*4)*64 + lane)*8;
    bf16x8 b0 = *(const bf16x8*)(wb);
    bf16x8 b1 = *(const bf16x8*)(wb + 512);
    bf16x8 b2 = *(const bf16x8*)(wb + 1024);
    bf16x8 b3 = *(const bf16x8*)(wb + 1536);
    acc2[0][0]=__builtin_amdgcn_mfma_f32_16x16x32_bf16(a0,b0,acc2[0][0],0,0,0);
    acc2[0][1]=__builtin_amdgcn_mfma_f32_16x16x32_bf16(a0,b1,acc2[0][1],0,0,0);
    acc2[0][2]=__builtin_amdgcn_mfma_f32_16x16x32_bf16(a0,b2,acc2[0][2],0,0,0);
    acc2[0][3]=__builtin_amdgcn_mfma_f32_16x16x32_bf16(a0,b3,acc2[0][3],0,0,0);
    acc2[1][0]=__builtin_amdgcn_mfma_f32_16x16x32_bf16(a1,b0,acc2[1][0],0,0,0);
    acc2[1][1]=__builtin_amdgcn_mfma_f32_16x16x32_bf16(a1,b1,acc2[1][1],0,0,0);
    acc2[1][2]=__builtin_amdgcn_mfma_f32_16x16x32_bf16(a1,b2,acc2[1][2],0,0,0);
    acc2[1][3]=__builtin_amdgcn_mfma_f32_16x16x32_bf16(a1,b3,acc2[1][3],0,0,0);
  }
  #pragma unroll
  for (int mt=0;mt<2;mt++)
  #pragma unroll
  for (int nt=0;nt<4;nt++){
    int n = wv*64 + nt*16 + nl;
    float bb = B2[l*HID + n];
    #pragma unroll
    for (int r=0;r<4;r++){
      int m = mt*16 + quad*4 + r;
      size_t idx = (size_t)(blk*32+m)*HID + n;
      float v = h[idx] + acc2[mt][nt][r] + bb;
      h[idx] = v;
      u16 bv = f2b(v);
      h_bf[idx] = bv;
      sH[m*264 + n] = bv;
    }
  }
  __syncthreads();

  const u16* Wl = cWab + (size_t)l*512*HID;
  f32x4 q[2][4];
  #pragma unroll
  for (int i=0;i<2;i++){ q[i][0]=zero4; q[i][1]=zero4; q[i][2]=zero4; q[i][3]=zero4; }
  #pragma unroll 2
  for (int k0=0;k0<8;k0++){
    bf16x8 a0 = *(const bf16x8*)(sH + (0*16+nl)*264 + k0*32 + quad*8);
    bf16x8 a1 = *(const bf16x8*)(sH + (1*16+nl)*264 + k0*32 + quad*8);
    const u16* wb = Wl + ((size_t)((k0+8)*16 + wv*4)*64 + lane)*8;
    bf16x8 b0 = *(const bf16x8*)(wb);
    bf16x8 b1 = *(const bf16x8*)(wb + 512);
    bf16x8 b2 = *(const bf16x8*)(wb + 1024);
    bf16x8 b3 = *(const bf16x8*)(wb + 1536);
    q[0][0]=__builtin_amdgcn_mfma_f32_16x16x32_bf16(a0,b0,q[0][0],0,0,0);
    q[0][1]=__builtin_amdgcn_mfma_f32_16x16x32_bf16(a0,b1,q[0][1],0,0,0);
    q[0][2]=__builtin_amdgcn_mfma_f32_16x16x32_bf16(a0,b2,q[0][2],0,0,0);
    q[0][3]=__builtin_amdgcn_mfma_f32_16x16x32_bf16(a0,b3,q[0][3],0,0,0);
    q[1][0]=__builtin_amdgcn_mfma_f32_16x16x32_bf16(a1,b0,q[1][0],0,0,0);
    q[1][1]=__builtin_amdgcn_mfma_f32_16x16x32_bf16(a1,b1,q[1][1],0,0,0);
    q[1][2]=__builtin_amdgcn_mfma_f32_16x16x32_bf16(a1,b2,q[1][2],0,0,0);
    q[1][3]=__builtin_amdgcn_mfma_f32_16x16x32_bf16(a1,b3,q[1][3],0,0,0);
  }
  #pragma unroll
  for (int mt=0;mt<2;mt++)
  #pragma unroll
  for (int nt=0;nt<4;nt++){
    int n = wv*64 + nt*16 + nl;
    #pragma unroll
    for (int r=0;r<4;r++){
      int node = blk*32 + mt*16 + quad*4 + r;
      QbC[(size_t)node*HID + n] = f2b(q[mt][nt][r]);
    }
  }
  if (blk < 32){
    #pragma unroll
    for (int i=0;i<2;i++){ q[i][0]=zero4; q[i][1]=zero4; q[i][2]=zero4; q[i][3]=zero4; }
    #pragma unroll 2
    for (int k0=0;k0<8;k0++){
      bf16x8 a0 = *(const bf16x8*)(sH + (0*16+nl)*264 + k0*32 + quad*8);
      bf16x8 a1 = *(const bf16x8*)(sH + (1*16+nl)*264 + k0*32 + quad*8);
      const u16* wb = Wl + ((size_t)(k0*16 + wv*4)*64 + lane)*8;
      bf16x8 b0 = *(const bf16x8*)(wb);
      bf16x8 b1 = *(const bf16x8*)(wb + 512);
      bf16x8 b2 = *(const bf16x8*)(wb + 1024);
      bf16x8 b3 = *(const bf16x8*)(wb + 1536);
      q[0][0]=__builtin_amdgcn_mfma_f32_16x16x32_bf16(a0,b0,q[0][0],0,0,0);
      q[0][1]=__builtin_amdgcn_mfma_f32_16x16x32_bf16(a0,b1,q[0][1],0,0,0);
      q[0][2]=__builtin_amdgcn_mfma_f32_16x16x32_bf16(a0,b2,q[0][2],0,0,0);
      q[0][3]=__builtin_amdgcn_mfma_f32_16x16x32_bf16(a0,b3,q[0][3],0,0,0);
      q[1][0]=__builtin_amdgcn_mfma_f32_16x16x32_bf16(a1,b0,q[1][0],0,0,0);
      q[1][1]=__builtin_amdgcn_mfma_f32_16x16x32_bf16(a1,b1,q[1][1],0,0,0);
      q[1][2]=__builtin_amdgcn_mfma_f32_16x16x32_bf16(a1,b2,q[1][2],0,0,0);
      q[1][3]=__builtin_amdgcn_mfma_f32_16x16x32_bf16(a1,b3,q[1][3],0,0,0);
    }
    #pragma unroll
    for (int mt=0;mt<2;mt++)
    #pragma unroll
    for (int nt=0;nt<4;nt++){
      int n = wv*64 + nt*16 + nl;
      #pragma unroll
      for (int r=0;r<4;r++){
        int node = blk*32 + mt*16 + quad*4 + r;
        RC[(size_t)node*HID + n] = q[mt][nt][r];
      }
    }
  }
  if (doE){
    #pragma unroll
    for (int i=0;i<2;i++){ q[i][0]=zero4; q[i][1]=zero4; q[i][2]=zero4; q[i][3]=zero4; }
    #pragma unroll 2
    for (int k0=0;k0<8;k0++){
      bf16x8 a0 = *(const bf16x8*)(sH + (0*16+nl)*264 + k0*32 + quad*8);
      bf16x8 a1 = *(const bf16x8*)(sH + (1*16+nl)*264 + k0*32 + quad*8);
      const u16* wb = eWabN + ((size_t)((k0+8)*16 + wv*4)*64 + lane)*8;
      bf16x8 b0 = *(const bf16x8*)(wb);
      bf16x8 b1 = *(const bf16x8*)(wb + 512);
      bf16x8 b2 = *(const bf16x8*)(wb + 1024);
      bf16x8 b3 = *(const bf16x8*)(wb + 1536);
      q[0][0]=__builtin_amdgcn_mfma_f32_16x16x32_bf16(a0,b0,q[0][0],0,0,0);
      q[0][1]=__builtin_amdgcn_mfma_f32_16x16x32_bf16(a0,b1,q[0][1],0,0,0);
      q[0][2]=__builtin_amdgcn_mfma_f32_16x16x32_bf16(a0,b2,q[0][2],0,0,0);
      q[0][3]=__builtin_amdgcn_mfma_f32_16x16x32_bf16(a0,b3,q[0][3],0,0,0);
      q[1][0]=__builtin_amdgcn_mfma_f32_16x16x32_bf16(a1,b0,q[1][0],0,0,0);
      q[1][1]=__builtin_amdgcn_mfma_f32_16x16x32_bf16(a1,b1,q[1][1],0,0,0);
      q[1][2]=__builtin_amdgcn_mfma_f32_16x16x32_bf16(a1,b2,q[1][2],0,0,0);
      q[1][3]=__builtin_amdgcn_mfma_f32_16x16x32_bf16(a1,b3,q[1][3],0,0,0);
    }
    #pragma unroll
    for (int mt=0;mt<2;mt++)
    #pragma unroll
    for (int nt=0;nt<4;nt++){
      int n = wv*64 + nt*16 + nl;
      #pragma unroll
      for (int r=0;r<4;r++){
        int node = blk*32 + mt*16 + quad*4 + r;
        QbE[(size_t)node*HID + n] = f2b(q[mt][nt][r]);
      }
    }
    if (blk < 32){
      #pragma unroll
      for (int i=0;i<2;i++){ q[i][0]=zero4; q[i][1]=zero4; q[i][2]=zero4; q[i][3]=zero4; }
      #pragma unroll 2
      for (int k0=0;k0<8;k0++){
        bf16x8 a0 = *(const bf16x8*)(sH + (0*16+nl)*264 + k0*32 + quad*8);
        bf16x8 a1 = *(const bf16x8*)(sH + (1*16+nl)*264 + k0*32 + quad*8);
        const u16* wb = eWabN + ((size_t)(k0*16 + wv*4)*64 + lane)*8;
        bf16x8 b0 = *(const bf16x8*)(wb);
        bf16x8 b1 = *(const bf16x8*)(wb + 512);
        bf16x8 b2 = *(const bf16x8*)(wb + 1024);
        bf16x8 b3 = *(const bf16x8*)(wb + 1536);
        q[0][0]=__builtin_amdgcn_mfma_f32_16x16x32_bf16(a0,b0,q[0][0],0,0,0);
        q[0][1]=__builtin_amdgcn_mfma_f32_16x16x32_bf16(a0,b1,q[0][1],0,0,0);
        q[0][2]=__builtin_amdgcn_mfma_f32_16x16x32_bf16(a0,b2,q[0][2],0,0,0);
        q[0][3]=__builtin_amdgcn_mfma_f32_16x16x32_bf16(a0,b3,q[0][3],0,0,0);
        q[1][0]=__builtin_amdgcn_mfma_f32_16x16x32_bf16(a1,b0,q[1][0],0,0,0);
        q[1][1]=__builtin_amdgcn_mfma_f32_16x16x32_bf16(a1,b1,q[1][1],0,0,0);
        q[1][2]=__builtin_amdgcn_mfma_f32_16x16x32_bf16(a1,b2,q[1][2],0,0,0);
        q[1][3]=__builtin_amdgcn_mfma_f32_16x16x32_bf16(a1,b3,q[1][3],0,0,0);
      }
      #pragma unroll
      for (int mt=0;mt<2;mt++)
      #pragma unroll
      for (int nt=0;nt<4;nt++){
        int n = wv*64 + nt*16 + nl;
        #pragma unroll
        for (int r=0;r<4;r++){
          int node = blk*32 + mt*16 + quad*4 + r;
          RE[(size_t)node*HID + n] = q[mt][nt][r];
        }
      }
    }
  }
  if (doOut && blk < 32){
    int mt = wv >> 1, ntw = wv & 1;
    f32x4 o = zero4;
    #pragma unroll 2
    for (int k0=0;k0<8;k0++){
      bf16x8 a = *(const bf16x8*)(sH + (mt*16+nl)*264 + k0*32 + quad*8);
      bf16x8 b = *(const bf16x8*)(WoutP + ((size_t)(k0*2 + ntw)*64 + lane)*8);
      o = __builtin_amdgcn_mfma_f32_16x16x32_bf16(a,b,o,0,0,0);
    }
    int n = ntw*16 + nl;
    float bb = bout[n];
    #pragma unroll
    for (int r=0;r<4;r++){
      int m = mt*16 + quad*4 + r;
      outH[(size_t)(blk*32+m)*32 + n] = o[r] + bb;
    }
  }
}

// ---- coord combine (48 edges/block, grid 1024) ----
__global__ __launch_bounds__(256) void k_comb_coord(
    const u16* __restrict__ Qb, const float* __restrict__ R,
    const float* __restrict__ xc, float* __restrict__ xn,
    const int* __restrict__ colIdx, const float* __restrict__ emb0,
    const u16* __restrict__ W1cP, const float* __restrict__ B1,
    const u16* __restrict__ W2p, const float* __restrict__ B2,
    const float* __restrict__ cW3,
    const float* __restrict__ posw, float* __restrict__ outX, int doOut, int l)
{
  __shared__ __align__(16) u16 sQ[48*264];
  __shared__ __align__(16) u16 sM1[48*264];
  __shared__ float sR[256];
  __shared__ int sCol[48];
  __shared__ float sD[48];
  __shared__ float sCd[48*3];
  __shared__ float sS[48];
  __shared__ float sDot[48][4];
  u16* sM2 = sQ;
  u16* sEA = sM1;

  int row = blockIdx.x, tid = threadIdx.x;
  int lane = tid & 63, ng = tid >> 6;
  int quad = lane >> 4, nl = lane & 15;

  if (tid < 48) sCol[tid] = colIdx[(size_t)row*KNN + tid];
  sR[tid] = R[(size_t)row*HID + tid];
  __syncthreads();
  for (int t = tid; t < 48*32; t += 256){
    int e = t >> 5, q = t & 31;
    uint4 v = ((const uint4*)(Qb + (size_t)sCol[e]*HID))[q];
    *(uint4*)(sQ + e*264 + q*8) = v;
  }
  if (tid < 48){
    int cg = sCol[tid];
    float dx = xc[row*3+0]-xc[cg*3+0];
    float dy = xc[row*3+1]-xc[cg*3+1];
    float dz = xc[row*3+2]-xc[cg*3+2];
    float d = sqrtf(dx*dx+dy*dy+dz*dz + 1e-8f);
    sD[tid] = d;
    float rden = __builtin_amdgcn_rcpf(d + 1.0f);
    sCd[tid*3+0]=dx*rden; sCd[tid*3+1]=dy*rden; sCd[tid*3+2]=dz*rden;
    u16* ea = sEA + tid*40;
    #pragma unroll
    for (int i=0;i<12;i++) ea[12+i] = f2b_p(emb0[((size_t)row*KNN + tid)*12 + i]);
    #pragma unroll
    for (int i=24;i<32;i++) ea[i] = 0;
  }
  __syncthreads();
  for (int t=tid; t<288; t+=256){
    int e = t/6, i = t - 6*e;
    float fr = 0.41887903f * (float)(1 << (2*i));
    float x = sD[e]*fr;
    u16* ea = sEA + e*40;
    ea[i]   = f2b(__sinf(x));
    ea[6+i] = f2b(__cosf(x));
  }
  __syncthreads();

  f32x4 zero4 = {0.f,0.f,0.f,0.f};
  f32x4 acc[3][4];
  #pragma unroll
  for (int i=0;i<3;i++){ acc[i][0]=zero4; acc[i][1]=zero4; acc[i][2]=zero4; acc[i][3]=zero4; }
  {
    const u16* Wc = W1cP + (size_t)l*32*HID;
    const u16* wb = Wc + ((size_t)(ng*4)*64 + lane)*8;
    bf16x8 b0 = *(const bf16x8*)(wb);
    bf16x8 b1 = *(const bf16x8*)(wb + 512);
    bf16x8 b2 = *(const bf16x8*)(wb + 1024);
    bf16x8 b3 = *(const bf16x8*)(wb + 1536);
    bf16x8 a0 = *(const bf16x8*)(sEA + (0*16+nl)*40 + quad*8);
    bf16x8 a1 = *(const bf16x8*)(sEA + (1*16+nl)*40 + quad*8);
    bf16x8 a2 = *(const bf16x8*)(sEA + (2*16+nl)*40 + quad*8);
    acc[0][0]=__builtin_amdgcn_mfma_f32_16x16x32_bf16(a0,b0,acc[0][0],0,0,0);
    acc[0][1]=__builtin_amdgcn_mfma_f32_16x16x32_bf16(a0,b1,acc[0][1],0,0,0);
    acc[0][2]=__builtin_amdgcn_mfma_f32_16x16x32_bf16(a0,b2,acc[0][2],0,0,0);
    acc[0][3]=__builtin_amdgcn_mfma_f32_16x16x32_bf16(a0,b3,acc[0][3],0,0,0);
    acc[1][0]=__builtin_amdgcn_mfma_f32_16x16x32_bf16(a1,b0,acc[1][0],0,0,0);
    acc[1][1]=__builtin_amdgcn_mfma_f32_16x16x32_bf16(a1,b1,acc[1][1],0,0,0);
    acc[1][2]=__builtin_amdgcn_mfma_f32_16x16x32_bf16(a1,b2,acc[1][2],0,0,0);
    acc[1][3]=__builtin_amdgcn_mfma_f32_16x16x32_bf16(a1,b3,acc[1][3],0,0,0);
    acc[2][0]=__builtin_amdgcn_mfma_f32_16x16x32_bf16(a2,b0,acc[2][0],0,0,0);
    acc[2][1]=__builtin_amdgcn_mfma_f32_16x16x32_bf16(a2,b1,acc[2][1],0,0,0);
    acc[2][2]=__builtin_amdgcn_mfma_f32_16x16x32_bf16(a2,b2,acc[2][2],0,0,0);
    acc[2][3]=__builtin_amdgcn_mfma_f32_16x16x32_bf16(a2,b3,acc[2][3],0,0,0);
  }
  __syncthreads();
  #pragma unroll
  for (int mt=0;mt<3;mt++)
  #pragma unroll
  for (int nt=0;nt<4;nt++){
    int n = ng*64 + nt*16 + nl;
    float bb = B1[l*HID + n] + sR[n];
    #pragma unroll
    for (int r=0;r<4;r++){
      int m = mt*16 + quad*4 + r;
      float v = acc[mt][nt][r] + bb + b2f(sQ[m*264 + n]);
      sM1[m*264 + n] = f2b(silu_f(v));
    }
  }
  __syncthreads();

  f32x4 acc2[3][4];
  #pragma unroll
  for (int i=0;i<3;i++){ acc2[i][0]=zero4; acc2[i][1]=zero4; acc2[i][2]=zero4; acc2[i][3]=zero4; }
  const u16* W2 = W2p + (size_t)l*HID*HID;
  #pragma unroll 2
  for (int k0=0;k0<8;k0++){
    bf16x8 a0 = *(const bf16x8*)(sM1 + (0*16+nl)*264 + k0*32 + quad*8);
    bf16x8 a1 = *(const bf16x8*)(sM1 + (1*16+nl)*264 + k0*32 + quad*8);
    bf16x8 a2 = *(const bf16x8*)(sM1 + (2*16+nl)*264 + k0*32 + quad*8);
    const u16* wb = W2 + ((size_t)(k0*16 + ng*4)*64 + lane)*8;
    bf16x8 b0 = *(const bf16x8*)(wb);
    bf16x8 b1 = *(const bf16x8*)(wb + 512);
    bf16x8 b2 = *(const bf16x8*)(wb + 1024);
    bf16x8 b3 = *(const bf16x8*)(wb + 1536);
    acc2[0][0]=__builtin_amdgcn_mfma_f32_16x16x32_bf16(a0,b0,acc2[0][0],0,0,0);
    acc2[0][1]=__builtin_amdgcn_mfma_f32_16x16x32_bf16(a0,b1,acc2[0][1],0,0,0);
    acc2[0][2]=__builtin_amdgcn_mfma_f32_16x16x32_bf16(a0,b2,acc2[0][2],0,0,0);
    acc2[0][3]=__builtin_amdgcn_mfma_f32_16x16x32_bf16(a0,b3,acc2[0][3],0,0,0);
    acc2[1][0]=__builtin_amdgcn_mfma_f32_16x16x32_bf16(a1,b0,acc2[1][0],0,0,0);
    acc2[1][1]=__builtin_amdgcn_mfma_f32_16x16x32_bf16(a1,b1,acc2[1][1],0,0,0);
    acc2[1][2]=__builtin_amdgcn_mfma_f32_16x16x32_bf16(a1,b2,acc2[1][2],0,0,0);
    acc2[1][3]=__builtin_amdgcn_mfma_f32_16x16x32_bf16(a1,b3,acc2[1][3],0,0,0);
    acc2[2][0]=__builtin_amdgcn_mfma_f32_16x16x32_bf16(a2,b0,acc2[2][0],0,0,0);
    acc2[2][1]=__builtin_amdgcn_mfma_f32_16x16x32_bf16(a2,b1,acc2[2][1],0,0,0);
    acc2[2][2]=__builtin_amdgcn_mfma_f32_16x16x32_bf16(a2,b2,acc2[2][2],0,0,0);
    acc2[2][3]=__builtin_amdgcn_mfma_f32_16x16x32_bf16(a2,b3,acc2[2][3],0,0,0);
  }
  #pragma unroll
  for (int mt=0;mt<3;mt++)
  #pragma unroll
  for (int nt=0;nt<4;nt++){
    int n = ng*64 + nt*16 + nl;
    float bb = B2[l*HID + n];
    #pragma unroll
    for (int r=0;r<4;r++){
      int m = mt*16 + quad*4 + r;
      sM2[m*264 + n] = f2b(silu_f(acc2[mt][nt][r] + bb));
    }
  }
  __syncthreads();
  if (tid < 192){
    int e = tid >> 2, qq = tid & 3;
    const unsigned int* rowp = (const unsigned int*)(sM2 + e*264 + qq*64);
    const float* wbase = cW3 + l*HID + qq*64;
    float s = 0.f;
    #pragma unroll 4
    for (int p0=0;p0<32;p0++){
      int p = (p0 + e + 8*qq) & 31;
      unsigned int v = rowp[p];
      s += b2f((u16)(v & 0xffffu))*wbase[2*p] + b2f((u16)(v >> 16))*wbase[2*p+1];
    }
    sDot[e][qq] = s;
  }
  __syncthreads();
  if (tid < 48) sS[tid] = sDot[tid][0]+sDot[tid][1]+sDot[tid][2]+sDot[tid][3];
  __syncthreads();
  if (tid < 3){
    float u = 0.f;
    #pragma unroll 4
    for (int e=0;e<48;e++) u += sCd[e*3+tid]*sS[e];
    float nv = xc[row*3+tid] + u*0.2f;
    xn[row*3+tid] = nv;
    if (doOut) outX[row*3+tid] = nv*posw[0];
  }
}

extern "C" void kernel_launch(void* const* d_in, const int* in_sizes, int n_in,
                              void* d_out, int out_size, void* d_ws, size_t ws_size,
                              hipStream_t stream)
{
  const float* protPos = (const float*)d_in[0];
  const int*   protEle = (const int*)d_in[1];
  const int*   protAA  = (const int*)d_in[2];
  const int*   protBB  = (const int*)d_in[3];
  const float* XtPos   = (const float*)d_in[4];
  const float* XtFeat  = (const float*)d_in[5];
  const int*   tArr    = (const int*)d_in[6];
  const float* WtTime  = (const float*)d_in[7];
  const float* Wele    = (const float*)d_in[8];
  const float* Waa     = (const float*)d_in[9];
  const float* Wbb     = (const float*)d_in[10];
  const float* Win     = (const float*)d_in[11];
  const float* bin     = (const float*)d_in[12];
  const float* Wout    = (const float*)d_in[13];
  const float* bout    = (const float*)d_in[14];
  const float* eW1     = (const float*)d_in[15];
  const float* eB1     = (const float*)d_in[16];
  const float* eW2     = (const float*)d_in[17];
  const float* eB2     = (const float*)d_in[18];
  const float* attW    = (const float*)d_in[19];
  const float* attB    = (const float*)d_in[20];
  const float* nW1     = (const float*)d_in[21];
  const float* nB1     = (const float*)d_in[22];
  const float* nW2     = (const float*)d_in[23];
  const float* nB2     = (const float*)d_in[24];
  const float* cW1     = (const float*)d_in[25];
  const float* cB1     = (const float*)d_in[26];
  const float* cW2     = (const float*)d_in[27];
  const float* cB2     = (const float*)d_in[28];
  const float* cW3     = (const float*)d_in[29];
  const float* posw    = (const float*)d_in[30];

  float* fp = (float*)d_ws;
  float* X0   = fp;               fp += NTOT*3;
  float* X1   = fp;               fp += NTOT*3;
  float* h    = fp;               fp += (size_t)NTOT*HID;
  float* emb0 = fp;               fp += (size_t)ETOT*12;
  float* RC   = fp;               fp += (size_t)N_LIGC*HID;
  float* RE   = fp;               fp += (size_t)N_LIGC*HID;
  int*   col  = (int*)fp;         fp += ETOT;
  u16*   up   = (u16*)fp;
  u16* h_bf   = up;               up += (size_t)NTOT*HID;
  u16* agg_bf = up;               up += (size_t)N_LIGC*HID;
  u16* QbE    = up;               up += (size_t)NTOT*HID;
  u16* QbC    = up;               up += (size_t)NTOT*HID;
  u16* eW1abP = up;               up += (size_t)DEPTHC*512*HID;
  u16* eW1cP  = up;               up += (size_t)DEPTHC*32*HID;
  u16* eW2p   = up;               up += (size_t)DEPTHC*HID*HID;
  u16* nW1p   = up;               up += (size_t)DEPTHC*512*HID;
  u16* nW2p   = up;               up += (size_t)DEPTHC*HID*HID;
  u16* cW1abP = up;               up += (size_t)DEPTHC*512*HID;
  u16* cW1cP  = up;               up += (size_t)DEPTHC*32*HID;
  u16* cW2p   = up;               up += (size_t)DEPTHC*HID*HID;
  u16* WoutP  = up;               up += (size_t)256*32;

  k_packall<<<1484,256,0,stream>>>(eW1,eW2,nW1,nW2,cW1,cW2,Wout,
      eW1abP,eW1cP,eW2p,nW1p,nW2p,cW1abP,cW1cP,cW2p,WoutP);
  k_embed_hinit<<<NTOT/8,256,0,stream>>>(protPos,protEle,protAA,protBB,XtPos,XtFeat,
      tArr,WtTime,Wele,Waa,Wbb,Win,bin,X0,X1,h,h_bf);
  k_knn<<<N_LIGC,256,0,stream>>>(X0,col,emb0);
  k_pq<<<NTOT/32,256,0,stream>>>(h_bf,eW1abP,RE,QbE,0);

  float* xc = X0; float* xn = X1;
  float* outF = (float*)d_out;
  for (int l=0;l<DEPTHC;l++){
    k_comb_edge<<<N_LIGC,256,0,stream>>>(QbE,RE,xc,col,emb0,eW1cP,eB1,eW2p,eB2,attW,attB,agg_bf,l);
    const u16* eNext = eW1abP + (size_t)((l+1)%DEPTHC)*512*HID;
    k_node<<<NTOT/32,256,0,stream>>>(h,h_bf,agg_bf,nW1p,nB1,nW2p,nB2,
        cW1abP,QbC,RC, eNext,QbE,RE,(l<DEPTHC-1)?1:0,
        WoutP,bout, outF+3072, (l==DEPTHC-1)?1:0, l);
    k_comb_coord<<<N_LIGC,256,0,stream>>>(QbC,RC,xc,xn,col,emb0,cW1cP,cB1,cW2p,cB2,cW3,
        posw, outF, (l==DEPTHC-1)?1:0, l);
    float* t2=xc; xc=xn; xn=t2;
  }
}